// Round 1
// baseline (301.748 us; speedup 1.0000x reference)
//
#include <hip/hip_runtime.h>
#include <cstdint>
#include <cstddef>

#define NN   32768
#define BATCH 16
#define LL   2048          // NN / BATCH
#define KNN  9
#define NE   (NN * KNN)    // 294912

// ---------------- helpers ----------------

__device__ __forceinline__ unsigned long long shfl_xor_u64(unsigned long long v, int mask) {
    int lo = (int)(unsigned)(v & 0xffffffffull);
    int hi = (int)(unsigned)(v >> 32);
    lo = __shfl_xor(lo, mask, 64);
    hi = __shfl_xor(hi, mask, 64);
    return ((unsigned long long)(unsigned)hi << 32) | (unsigned)lo;
}

// Distance exactly like the reference: sqrt(((dx*dx + dy*dy) + dz*dz) + 1e-6)
// using explicit non-fused rounding so FMA contraction can't change ordering.
__device__ __forceinline__ float ref_dist(float ax, float ay, float az,
                                          float bx, float by, float bz) {
    float dx = __fsub_rn(ax, bx);
    float dy = __fsub_rn(ay, by);
    float dz = __fsub_rn(az, bz);
    float d2 = __fadd_rn(__fadd_rn(__fmul_rn(dx, dx), __fmul_rn(dy, dy)),
                         __fmul_rn(dz, dz));
    return sqrtf(__fadd_rn(d2, 1e-6f));
}

__device__ __forceinline__ float rbf_val(float d, int t) {
    // mu = linspace(0,20,16) -> t * (20/15); sigma = 20/16 = 1.25
    float mu = (float)t * (20.0f / 15.0f);
    float z = (d - mu) * 0.8f;   // /1.25
    return __expf(-z * z);
}

// ---------------- kernel 0: normalize is_global to int32 ----------------
// The harness may hand us bool as packed uint8 or as int32. Detect: OR the
// first NN/4 words; packed random 0/1 bytes make some word > 1 (prob ~1-8^-8192),
// while int32 bools are all 0/1.
__global__ __launch_bounds__(1024) void expand_isg_kernel(const int* __restrict__ raw,
                                                          int* __restrict__ out) {
    __shared__ int flag;
    if (threadIdx.x == 0) flag = 0;
    __syncthreads();
    unsigned v = 0;
    for (int t = threadIdx.x; t < NN / 4; t += 1024) v |= (unsigned)raw[t];
    if (v > 1u) atomicOr(&flag, 1);
    __syncthreads();
    if (flag) {
        const unsigned char* b = (const unsigned char*)raw;
        for (int t = threadIdx.x; t < NN; t += 1024) out[t] = b[t] ? 1 : 0;
    } else {
        for (int t = threadIdx.x; t < NN; t += 1024) out[t] = raw[t] ? 1 : 0;
    }
}

// ---------------- kernel 1: per-batch KNN + row/col/masks ----------------
// One wave per query row; 4 rows (same batch) per 256-thread block.
// Batch CA coords staged in LDS (SoA: 3 * 2048 * 4B = 24 KB).
__global__ __launch_bounds__(256) void knn_kernel(
    const float* __restrict__ X, const int* __restrict__ seg,
    const int* __restrict__ isg, int* __restrict__ col_int,
    float* __restrict__ out_row, float* __restrict__ out_col,
    float* __restrict__ out_ctx, float* __restrict__ out_inter)
{
    __shared__ float xs[LL], ys[LL], zs[LL];
    int row0 = blockIdx.x * 4;
    int b    = row0 >> 11;            // / LL
    int base = b << 11;
    for (int t = threadIdx.x; t < LL; t += 256) {
        const float* p = X + (size_t)(base + t) * 12 + 3;   // atom 1 (CA)
        xs[t] = p[0]; ys[t] = p[1]; zs[t] = p[2];
    }
    __syncthreads();

    int lane = threadIdx.x & 63;
    int gi   = row0 + (threadIdx.x >> 6);   // global node index
    int i    = gi - base;                   // local row within batch
    float xi = xs[i], yi = ys[i], zi = zs[i];

    // per-lane sorted top-9 of packed (dist_bits, idx)
    unsigned long long lst[KNN];
#pragma unroll
    for (int k = 0; k < KNN; ++k) lst[k] = ~0ull;

    for (int s = 0; s < LL / 64; ++s) {
        int j = (s << 6) + lane;
        float d = ref_dist(xi, yi, zi, xs[j], ys[j], zs[j]);
        unsigned long long p =
            ((unsigned long long)__float_as_uint(d) << 32) | (unsigned)j;
        if (p < lst[KNN - 1]) {
            int k = KNN - 1;
            while (k > 0 && lst[k - 1] > p) { lst[k] = lst[k - 1]; --k; }
            lst[k] = p;
        }
    }

    // merge across the wave: 9 rounds of butterfly-min; lane r keeps round-r winner
    int pos = 0;
    unsigned long long mine = 0;
    for (int r = 0; r < KNN; ++r) {
        unsigned long long cand = lst[pos];
        unsigned long long m = cand;
#pragma unroll
        for (int off = 32; off >= 1; off >>= 1) {
            unsigned long long o = shfl_xor_u64(m, off);
            if (o < m) m = o;
        }
        if (m == cand) ++pos;     // packed values unique (distinct j per lane)
        if (lane == r) mine = m;
    }

    if (lane < KNN) {
        int j  = (int)(unsigned)(mine & 0xffffffffu);
        int cg = base + j;
        int e  = gi * KNN + lane;
        col_int[e]  = cg;
        out_row[e]  = (float)gi;
        out_col[e]  = (float)cg;
        int sr = seg[gi], sc = seg[cg];
        int ng = (isg[gi] | isg[cg]) ? 0 : 1;
        out_ctx[e]   = (sr == sc && ng) ? 1.0f : 0.0f;
        out_inter[e] = (sr != sc && ng) ? 1.0f : 0.0f;
    }
}

// ---------------- kernel 2: node RBF features [N, 48] ----------------
__global__ __launch_bounds__(256) void node_kernel(const float* __restrict__ X,
                                                   float* __restrict__ out) {
    int n = blockIdx.x * 256 + threadIdx.x;
    if (n >= NN) return;
    const float* p = X + (size_t)n * 12;
    float a0x = p[0],  a0y = p[1],  a0z = p[2];
    float a1x = p[3],  a1y = p[4],  a1z = p[5];
    float a2x = p[6],  a2y = p[7],  a2z = p[8];
    float a3x = p[9],  a3y = p[10], a3z = p[11];
    float d[3];
    d[0] = ref_dist(a0x, a0y, a0z, a1x, a1y, a1z);
    d[1] = ref_dist(a2x, a2y, a2z, a1x, a1y, a1z);
    d[2] = ref_dist(a3x, a3y, a3z, a1x, a1y, a1z);
    float buf[48];
#pragma unroll
    for (int a = 0; a < 3; ++a)
#pragma unroll
        for (int t = 0; t < 16; ++t)
            buf[a * 16 + t] = rbf_val(d[a], t);
    float4* o = (float4*)(out + (size_t)n * 48);
#pragma unroll
    for (int q = 0; q < 12; ++q)
        o[q] = make_float4(buf[q * 4], buf[q * 4 + 1], buf[q * 4 + 2], buf[q * 4 + 3]);
}

// ---------------- kernel 3: edge RBF features [N*K, 64] ----------------
// One wave per edge; lane f: atom = f>>4, rbf center = f&15. Coalesced stores.
__global__ __launch_bounds__(256) void edge_kernel(const float* __restrict__ X,
                                                   const int* __restrict__ col_int,
                                                   float* __restrict__ out) {
    int gtid = blockIdx.x * 256 + threadIdx.x;
    int e = gtid >> 6;
    int f = gtid & 63;
    if (e >= NE) return;
    int row = e / KNN;
    int cg  = col_int[e];
    int atom = f >> 4, t = f & 15;
    const float* pr = X + (size_t)row * 12 + atom * 3;
    const float* pc = X + (size_t)cg * 12 + 3;
    float d = ref_dist(pr[0], pr[1], pr[2], pc[0], pc[1], pc[2]);
    out[(size_t)e * 64 + f] = rbf_val(d, t);
}

// ---------------- launcher ----------------
extern "C" void kernel_launch(void* const* d_in, const int* in_sizes, int n_in,
                              void* d_out, int out_size, void* d_ws, size_t ws_size,
                              hipStream_t stream) {
    const float* X       = (const float*)d_in[0];
    const int*   seg     = (const int*)d_in[1];
    const int*   isg_raw = (const int*)d_in[2];

    float* out = (float*)d_out;
    float* node_out  = out;                                   // [NN*48]
    float* edge_out  = out + (size_t)NN * 48;                 // [NE*64]
    float* row_out   = edge_out + (size_t)NE * 64;            // [NE]
    float* col_out   = row_out + NE;                          // [NE]
    float* ctx_out   = col_out + NE;                          // [NE]
    float* inter_out = ctx_out + NE;                          // [NE]

    int* isg     = (int*)d_ws;            // [NN] expanded is_global
    int* col_int = (int*)d_ws + NN;       // [NE] global col indices

    hipLaunchKernelGGL(expand_isg_kernel, dim3(1), dim3(1024), 0, stream,
                       isg_raw, isg);
    hipLaunchKernelGGL(knn_kernel, dim3(NN / 4), dim3(256), 0, stream,
                       X, seg, isg, col_int, row_out, col_out, ctx_out, inter_out);
    hipLaunchKernelGGL(node_kernel, dim3(NN / 256), dim3(256), 0, stream,
                       X, node_out);
    hipLaunchKernelGGL(edge_kernel, dim3((NE * 64) / 256), dim3(256), 0, stream,
                       X, col_int, edge_out);
}

// Round 2
// 130.624 us; speedup vs baseline: 2.3100x; 2.3100x over previous
//
#include <hip/hip_runtime.h>
#include <cstdint>
#include <cstddef>

#define NN   32768
#define BATCH 16
#define LL   2048          // NN / BATCH
#define KNN  9
#define NE   (NN * KNN)    // 294912
#define PLM  8             // per-lane list size
#define MTOP 12            // global candidates extracted before exact resort

// ---------------- helpers ----------------

// Squared distance with explicit non-fused rounding, fixed association:
// ((dx*dx + dy*dy) + dz*dz) — must match everywhere for deterministic ordering.
__device__ __forceinline__ float ref_d2(float ax, float ay, float az,
                                        float bx, float by, float bz) {
    float dx = __fsub_rn(ax, bx);
    float dy = __fsub_rn(ay, by);
    float dz = __fsub_rn(az, bz);
    return __fadd_rn(__fadd_rn(__fmul_rn(dx, dx), __fmul_rn(dy, dy)),
                     __fmul_rn(dz, dz));
}

__device__ __forceinline__ float ref_dist(float ax, float ay, float az,
                                          float bx, float by, float bz) {
    return sqrtf(__fadd_rn(ref_d2(ax, ay, az, bx, by, bz), 1e-6f));
}

__device__ __forceinline__ float rbf_val(float d, int t) {
    // mu = linspace(0,20,16) -> t * (20/15); sigma = 20/16 = 1.25
    float mu = (float)t * (20.0f / 15.0f);
    float z = (d - mu) * 0.8f;   // /1.25
    return __expf(-z * z);
}

// ---------------- kernel 0: normalize is_global to int32 ----------------
__global__ __launch_bounds__(1024) void expand_isg_kernel(const int* __restrict__ raw,
                                                          int* __restrict__ out) {
    __shared__ int flag;
    if (threadIdx.x == 0) flag = 0;
    __syncthreads();
    unsigned v = 0;
    for (int t = threadIdx.x; t < NN / 4; t += 1024) v |= (unsigned)raw[t];
    if (v > 1u) atomicOr(&flag, 1);
    __syncthreads();
    if (flag) {
        const unsigned char* b = (const unsigned char*)raw;
        for (int t = threadIdx.x; t < NN; t += 1024) out[t] = b[t] ? 1 : 0;
    } else {
        for (int t = threadIdx.x; t < NN; t += 1024) out[t] = raw[t] ? 1 : 0;
    }
}

// ---------------- kernel 1: per-batch KNN + row/col/masks ----------------
// One wave per query row; 4 rows (same batch) per 256-thread block.
// Scan phase: branchless per-lane top-8 of 32-bit keys (trunc d2 | idx).
// Merge phase: 12 butterfly-min extractions with branchless head removal.
// Resort phase: exact (sqrt(d2+eps), j) ranking of the 12 finalists.
__global__ __launch_bounds__(256) void knn_kernel(
    const float* __restrict__ X, const int* __restrict__ seg,
    const int* __restrict__ isg, int* __restrict__ col_int,
    float* __restrict__ out_row, float* __restrict__ out_col,
    float* __restrict__ out_ctx, float* __restrict__ out_inter)
{
    __shared__ float crd[3 * LL];   // [x | y | z] SoA, 24 KB
    int row0 = blockIdx.x * 4;
    int base = row0 & ~(LL - 1);
    for (int t = threadIdx.x; t < LL; t += 256) {
        const float* p = X + (size_t)(base + t) * 12 + 3;   // atom 1 (CA)
        crd[t] = p[0]; crd[t + LL] = p[1]; crd[t + 2 * LL] = p[2];
    }
    __syncthreads();

    int lane = threadIdx.x & 63;
    int gi   = row0 + (threadIdx.x >> 6);
    int i    = gi - base;
    float xi = crd[i], yi = crd[i + LL], zi = crd[i + 2 * LL];

    unsigned lst[PLM];
#pragma unroll
    for (int k = 0; k < PLM; ++k) lst[k] = 0xFFFFFFFFu;

#pragma unroll 4
    for (int s = 0; s < LL / 64; ++s) {
        int j = (s << 6) + lane;
        float xj = crd[j], yj = crd[j + LL], zj = crd[j + 2 * LL];
        float d2 = ref_d2(xi, yi, zi, xj, yj, zj);
        unsigned key = (__float_as_uint(d2) & 0xFFFFF800u) | (unsigned)j;
        // branchless sorted insert (ascending; lst[0] smallest)
        bool c[PLM];
#pragma unroll
        for (int k = 0; k < PLM; ++k) c[k] = key < lst[k];
#pragma unroll
        for (int k = PLM - 1; k >= 1; --k)
            lst[k] = c[k - 1] ? lst[k - 1] : (c[k] ? key : lst[k]);
        lst[0] = c[0] ? key : lst[0];
    }

    // extract the MTOP globally-smallest keys; lane r ends with the r-th
    unsigned mine = 0xFFFFFFFFu;
#pragma unroll
    for (int r = 0; r < MTOP; ++r) {
        unsigned m = lst[0];
#pragma unroll
        for (int off = 32; off >= 1; off >>= 1)
            m = min(m, (unsigned)__shfl_xor((int)m, off, 64));
        bool rem = (lst[0] == m);       // unique key -> at most one lane
#pragma unroll
        for (int k = 0; k < PLM - 1; ++k) lst[k] = rem ? lst[k + 1] : lst[k];
        lst[PLM - 1] = rem ? 0xFFFFFFFFu : lst[PLM - 1];
        if (lane == r) mine = m;
    }

    // exact resort of the MTOP finalists by (D = sqrt(d2+eps), j)
    int jf = (int)(mine & (LL - 1));
    float xj = crd[jf], yj = crd[jf + LL], zj = crd[jf + 2 * LL];
    float D = sqrtf(__fadd_rn(ref_d2(xi, yi, zi, xj, yj, zj), 1e-6f));
    int rank = 0;
#pragma unroll
    for (int t = 0; t < MTOP; ++t) {
        float Dt = __shfl(D, t, 64);
        int   jt = __shfl(jf, t, 64);
        bool lt = (Dt < D) || (Dt == D && jt < jf);
        rank += lt ? 1 : 0;
    }

    if (lane < MTOP && rank < KNN) {
        int cg = base + jf;
        int e  = gi * KNN + rank;
        col_int[e]  = cg;
        out_row[e]  = (float)gi;
        out_col[e]  = (float)cg;
        int sr = seg[gi], sc = seg[cg];
        int ng = (isg[gi] | isg[cg]) ? 0 : 1;
        out_ctx[e]   = (sr == sc && ng) ? 1.0f : 0.0f;
        out_inter[e] = (sr != sc && ng) ? 1.0f : 0.0f;
    }
}

// ---------------- kernel 2: node RBF features [N, 48] ----------------
__global__ __launch_bounds__(256) void node_kernel(const float* __restrict__ X,
                                                   float* __restrict__ out) {
    int n = blockIdx.x * 256 + threadIdx.x;
    if (n >= NN) return;
    const float* p = X + (size_t)n * 12;
    float d[3];
    d[0] = ref_dist(p[0], p[1],  p[2],  p[3], p[4], p[5]);
    d[1] = ref_dist(p[6], p[7],  p[8],  p[3], p[4], p[5]);
    d[2] = ref_dist(p[9], p[10], p[11], p[3], p[4], p[5]);
    float buf[48];
#pragma unroll
    for (int a = 0; a < 3; ++a)
#pragma unroll
        for (int t = 0; t < 16; ++t)
            buf[a * 16 + t] = rbf_val(d[a], t);
    float4* o = (float4*)(out + (size_t)n * 48);
#pragma unroll
    for (int q = 0; q < 12; ++q)
        o[q] = make_float4(buf[q * 4], buf[q * 4 + 1], buf[q * 4 + 2], buf[q * 4 + 3]);
}

// ---------------- kernel 3: edge RBF features [N*K, 64] ----------------
__global__ __launch_bounds__(256) void edge_kernel(const float* __restrict__ X,
                                                   const int* __restrict__ col_int,
                                                   float* __restrict__ out) {
    int gtid = blockIdx.x * 256 + threadIdx.x;
    int e = gtid >> 6;
    int f = gtid & 63;
    if (e >= NE) return;
    int row = e / KNN;
    int cg  = col_int[e];
    int atom = f >> 4, t = f & 15;
    const float* pr = X + (size_t)row * 12 + atom * 3;
    const float* pc = X + (size_t)cg * 12 + 3;
    float d = ref_dist(pr[0], pr[1], pr[2], pc[0], pc[1], pc[2]);
    out[(size_t)e * 64 + f] = rbf_val(d, t);
}

// ---------------- launcher ----------------
extern "C" void kernel_launch(void* const* d_in, const int* in_sizes, int n_in,
                              void* d_out, int out_size, void* d_ws, size_t ws_size,
                              hipStream_t stream) {
    const float* X       = (const float*)d_in[0];
    const int*   seg     = (const int*)d_in[1];
    const int*   isg_raw = (const int*)d_in[2];

    float* out = (float*)d_out;
    float* node_out  = out;                                   // [NN*48]
    float* edge_out  = out + (size_t)NN * 48;                 // [NE*64]
    float* row_out   = edge_out + (size_t)NE * 64;            // [NE]
    float* col_out   = row_out + NE;                          // [NE]
    float* ctx_out   = col_out + NE;                          // [NE]
    float* inter_out = ctx_out + NE;                          // [NE]

    int* isg     = (int*)d_ws;            // [NN] expanded is_global
    int* col_int = (int*)d_ws + NN;       // [NE] global col indices

    hipLaunchKernelGGL(expand_isg_kernel, dim3(1), dim3(1024), 0, stream,
                       isg_raw, isg);
    hipLaunchKernelGGL(knn_kernel, dim3(NN / 4), dim3(256), 0, stream,
                       X, seg, isg, col_int, row_out, col_out, ctx_out, inter_out);
    hipLaunchKernelGGL(node_kernel, dim3(NN / 256), dim3(256), 0, stream,
                       X, node_out);
    hipLaunchKernelGGL(edge_kernel, dim3((NE * 64) / 256), dim3(256), 0, stream,
                       X, col_int, edge_out);
}

// Round 3
// 110.866 us; speedup vs baseline: 2.7217x; 1.1782x over previous
//
#include <hip/hip_runtime.h>
#include <cstdint>
#include <cstddef>

#define NN   32768
#define BATCH 16
#define LL   2048          // NN / BATCH
#define KNN  9
#define NE   (NN * KNN)    // 294912
#define PLM  6             // per-lane list size
#define MTOP 12            // global candidates extracted before exact resort

// ---------------- helpers ----------------

// Reference-exact squared distance (non-fused, fixed association).
__device__ __forceinline__ float ref_d2(float ax, float ay, float az,
                                        float bx, float by, float bz) {
    float dx = __fsub_rn(ax, bx);
    float dy = __fsub_rn(ay, by);
    float dz = __fsub_rn(az, bz);
    return __fadd_rn(__fadd_rn(__fmul_rn(dx, dx), __fmul_rn(dy, dy)),
                     __fmul_rn(dz, dz));
}

__device__ __forceinline__ float ref_dist(float ax, float ay, float az,
                                          float bx, float by, float bz) {
    return sqrtf(__fadd_rn(ref_d2(ax, ay, az, bx, by, bz), 1e-6f));
}

__device__ __forceinline__ float rbf_val(float d, int t) {
    // mu = linspace(0,20,16) -> t * (20/15); sigma = 20/16 = 1.25
    float mu = (float)t * (20.0f / 15.0f);
    float z = (d - mu) * 0.8f;   // /1.25
    return __expf(-z * z);
}

// ---------------- kernel 0: normalize is_global to int32 ----------------
__global__ __launch_bounds__(1024) void expand_isg_kernel(const int* __restrict__ raw,
                                                          int* __restrict__ out) {
    __shared__ int flag;
    if (threadIdx.x == 0) flag = 0;
    __syncthreads();
    unsigned v = 0;
    for (int t = threadIdx.x; t < NN / 4; t += 1024) v |= (unsigned)raw[t];
    if (v > 1u) atomicOr(&flag, 1);
    __syncthreads();
    if (flag) {
        const unsigned char* b = (const unsigned char*)raw;
        for (int t = threadIdx.x; t < NN; t += 1024) out[t] = b[t] ? 1 : 0;
    } else {
        for (int t = threadIdx.x; t < NN; t += 1024) out[t] = raw[t] ? 1 : 0;
    }
}

// ---------------- kernel 1: per-batch KNN + row/col/masks ----------------
// One wave per query row; 8 rows (same batch) per 512-thread block.
// Scan: approx d2 via (ni+nj-2*dot) fma, 21-bit-truncated key | index,
//       mask-free min/max bubble insert into per-lane sorted top-6.
// Merge: 12 butterfly-min extractions with branchless head removal.
// Resort: exact (sqrt(ref_d2+eps), j) ranking of the 12 finalists.
__global__ __launch_bounds__(512) void knn_kernel(
    const float* __restrict__ X, const int* __restrict__ seg,
    const int* __restrict__ isg, int* __restrict__ col_int,
    float* __restrict__ out_row, float* __restrict__ out_col,
    float* __restrict__ out_ctx, float* __restrict__ out_inter)
{
    __shared__ float4 crd[LL];   // x, y, z, |p|^2  (32 KB)
    int row0 = blockIdx.x * 8;
    int base = row0 & ~(LL - 1);
    for (int t = threadIdx.x; t < LL; t += 512) {
        const float* p = X + (size_t)(base + t) * 12 + 3;   // atom 1 (CA)
        float x = p[0], y = p[1], z = p[2];
        crd[t] = make_float4(x, y, z, fmaf(x, x, fmaf(y, y, z * z)));
    }
    __syncthreads();

    int lane = threadIdx.x & 63;
    int gi   = row0 + (threadIdx.x >> 6);
    int i    = gi - base;
    float4 ci = crd[i];
    float xi = ci.x, yi = ci.y, zi = ci.z, ni = ci.w;

    unsigned lst[PLM];
#pragma unroll
    for (int k = 0; k < PLM; ++k) lst[k] = 0xFFFFFFFFu;

#pragma unroll 4
    for (int s = 0; s < LL / 64; ++s) {
        int j = (s << 6) + lane;
        float4 c = crd[j];
        float dot = fmaf(xi, c.x, fmaf(yi, c.y, zi * c.z));
        float d2  = fmaf(-2.0f, dot, ni + c.w);
        d2 = fmaxf(d2, 0.0f);     // self-pair cancels to exactly 0; guard tiny negatives
        unsigned cur = (__float_as_uint(d2) & 0xFFFFF800u) | (unsigned)j;
        // mask-free sorted insert (ascending; lst[0] smallest)
#pragma unroll
        for (int k = 0; k < PLM; ++k) {
            unsigned lo = min(lst[k], cur);
            cur = max(lst[k], cur);
            lst[k] = lo;
        }
    }

    // extract the MTOP globally-smallest keys; lane r ends with the r-th
    unsigned mine = 0xFFFFFFFFu;
#pragma unroll
    for (int r = 0; r < MTOP; ++r) {
        unsigned m = lst[0];
#pragma unroll
        for (int off = 32; off >= 1; off >>= 1)
            m = min(m, (unsigned)__shfl_xor((int)m, off, 64));
        bool rem = (lst[0] == m);       // keys unique -> at most one lane
#pragma unroll
        for (int k = 0; k < PLM - 1; ++k) lst[k] = rem ? lst[k + 1] : lst[k];
        lst[PLM - 1] = rem ? 0xFFFFFFFFu : lst[PLM - 1];
        if (lane == r) mine = m;
    }

    // exact resort of the MTOP finalists by (D = sqrt(ref_d2 + eps), j)
    int jf = (int)(mine & (LL - 1));
    float4 cj = crd[jf];
    float D = sqrtf(__fadd_rn(ref_d2(xi, yi, zi, cj.x, cj.y, cj.z), 1e-6f));
    int rank = 0;
#pragma unroll
    for (int t = 0; t < MTOP; ++t) {
        float Dt = __shfl(D, t, 64);
        int   jt = __shfl(jf, t, 64);
        bool lt = (Dt < D) || (Dt == D && jt < jf);
        rank += lt ? 1 : 0;
    }

    if (lane < MTOP && rank < KNN) {
        int cg = base + jf;
        int e  = gi * KNN + rank;
        col_int[e]  = cg;
        out_row[e]  = (float)gi;
        out_col[e]  = (float)cg;
        int sr = seg[gi], sc = seg[cg];
        int ng = (isg[gi] | isg[cg]) ? 0 : 1;
        out_ctx[e]   = (sr == sc && ng) ? 1.0f : 0.0f;
        out_inter[e] = (sr != sc && ng) ? 1.0f : 0.0f;
    }
}

// ---------------- kernel 2: node RBF features [N, 48] ----------------
__global__ __launch_bounds__(256) void node_kernel(const float* __restrict__ X,
                                                   float* __restrict__ out) {
    int n = blockIdx.x * 256 + threadIdx.x;
    if (n >= NN) return;
    const float* p = X + (size_t)n * 12;
    float d[3];
    d[0] = ref_dist(p[0], p[1],  p[2],  p[3], p[4], p[5]);
    d[1] = ref_dist(p[6], p[7],  p[8],  p[3], p[4], p[5]);
    d[2] = ref_dist(p[9], p[10], p[11], p[3], p[4], p[5]);
    float buf[48];
#pragma unroll
    for (int a = 0; a < 3; ++a)
#pragma unroll
        for (int t = 0; t < 16; ++t)
            buf[a * 16 + t] = rbf_val(d[a], t);
    float4* o = (float4*)(out + (size_t)n * 48);
#pragma unroll
    for (int q = 0; q < 12; ++q)
        o[q] = make_float4(buf[q * 4], buf[q * 4 + 1], buf[q * 4 + 2], buf[q * 4 + 3]);
}

// ---------------- kernel 3: edge RBF features [N*K, 64] ----------------
// One wave per edge; lane f: atom = f>>4, rbf center = f&15. Coalesced stores.
__global__ __launch_bounds__(256) void edge_kernel(const float* __restrict__ X,
                                                   const int* __restrict__ col_int,
                                                   float* __restrict__ out) {
    int gtid = blockIdx.x * 256 + threadIdx.x;
    int e = gtid >> 6;
    int f = gtid & 63;
    if (e >= NE) return;
    int row = e / KNN;
    int cg  = col_int[e];
    int atom = f >> 4, t = f & 15;
    const float* pr = X + (size_t)row * 12 + atom * 3;
    const float* pc = X + (size_t)cg * 12 + 3;
    float d = ref_dist(pr[0], pr[1], pr[2], pc[0], pc[1], pc[2]);
    out[(size_t)e * 64 + f] = rbf_val(d, t);
}

// ---------------- launcher ----------------
extern "C" void kernel_launch(void* const* d_in, const int* in_sizes, int n_in,
                              void* d_out, int out_size, void* d_ws, size_t ws_size,
                              hipStream_t stream) {
    const float* X       = (const float*)d_in[0];
    const int*   seg     = (const int*)d_in[1];
    const int*   isg_raw = (const int*)d_in[2];

    float* out = (float*)d_out;
    float* node_out  = out;                                   // [NN*48]
    float* edge_out  = out + (size_t)NN * 48;                 // [NE*64]
    float* row_out   = edge_out + (size_t)NE * 64;            // [NE]
    float* col_out   = row_out + NE;                          // [NE]
    float* ctx_out   = col_out + NE;                          // [NE]
    float* inter_out = ctx_out + NE;                          // [NE]

    int* isg     = (int*)d_ws;            // [NN] expanded is_global
    int* col_int = (int*)d_ws + NN;       // [NE] global col indices

    hipLaunchKernelGGL(expand_isg_kernel, dim3(1), dim3(1024), 0, stream,
                       isg_raw, isg);
    hipLaunchKernelGGL(knn_kernel, dim3(NN / 8), dim3(512), 0, stream,
                       X, seg, isg, col_int, row_out, col_out, ctx_out, inter_out);
    hipLaunchKernelGGL(node_kernel, dim3(NN / 256), dim3(256), 0, stream,
                       X, node_out);
    hipLaunchKernelGGL(edge_kernel, dim3((NE * 64) / 256), dim3(256), 0, stream,
                       X, col_int, edge_out);
}

// Round 4
// 107.371 us; speedup vs baseline: 2.8103x; 1.0326x over previous
//
#include <hip/hip_runtime.h>
#include <cstdint>
#include <cstddef>

#define NN   32768
#define BATCH 16
#define LL   2048          // NN / BATCH
#define KNN  9
#define NE   (NN * KNN)    // 294912
#define PLM  5             // per-lane list size
#define MTOP 12            // global candidates extracted before exact resort
#define RPW  4             // rows per wave (scan amortization)

// ---------------- helpers ----------------

// Reference-exact squared distance (non-fused, fixed association).
__device__ __forceinline__ float ref_d2(float ax, float ay, float az,
                                        float bx, float by, float bz) {
    float dx = __fsub_rn(ax, bx);
    float dy = __fsub_rn(ay, by);
    float dz = __fsub_rn(az, bz);
    return __fadd_rn(__fadd_rn(__fmul_rn(dx, dx), __fmul_rn(dy, dy)),
                     __fmul_rn(dz, dz));
}

__device__ __forceinline__ float ref_dist(float ax, float ay, float az,
                                          float bx, float by, float bz) {
    return sqrtf(__fadd_rn(ref_d2(ax, ay, az, bx, by, bz), 1e-6f));
}

__device__ __forceinline__ float rbf_val(float d, int t) {
    // mu = linspace(0,20,16) -> t * (20/15); sigma = 20/16 = 1.25
    float mu = (float)t * (20.0f / 15.0f);
    float z = (d - mu) * 0.8f;   // /1.25
    return __expf(-z * z);
}

// ---------------- kernel 0: normalize is_global to int32 ----------------
// 32 blocks x 256 threads. Per-block dtype detection: scan 256 words of the
// block's own region; packed random 0/1 bytes give a word>1 with
// P = 1 - 8^-256 (certain), int32 bools never do. No cross-block comms needed.
__global__ __launch_bounds__(256) void expand_isg_kernel(const int* __restrict__ raw,
                                                         int* __restrict__ out) {
    __shared__ int flag;
    if (threadIdx.x == 0) flag = 0;
    __syncthreads();
    unsigned v = (unsigned)raw[blockIdx.x * 256 + threadIdx.x];
    if (v > 1u) atomicOr(&flag, 1);
    __syncthreads();
    int t0 = blockIdx.x * 1024;
    if (flag) {
        const unsigned char* b = (const unsigned char*)raw;
        for (int t = threadIdx.x; t < 1024; t += 256) out[t0 + t] = b[t0 + t] ? 1 : 0;
    } else {
        for (int t = threadIdx.x; t < 1024; t += 256) out[t0 + t] = raw[t0 + t] ? 1 : 0;
    }
}

// ---------------- kernel 1: per-batch KNN + row/col/masks ----------------
// One wave handles RPW=4 consecutive rows; 512-thread block = 32 rows.
// Scan: one ds_read_b128 per candidate reused across 4 rows (regs);
//       approx d2 via (ni+nj-2*dot) fma; 21-bit truncated key | index;
//       mask-free min/max bubble insert into per-lane sorted top-5.
// Merge (per row): 12 butterfly-min extractions, branchless head removal.
// Resort (per row): exact (sqrt(ref_d2+eps), j) ranking of the 12 finalists.
__global__ __launch_bounds__(512) void knn_kernel(
    const float* __restrict__ X, const int* __restrict__ seg,
    const int* __restrict__ isg, int* __restrict__ col_int,
    float* __restrict__ out_row, float* __restrict__ out_col,
    float* __restrict__ out_ctx, float* __restrict__ out_inter)
{
    __shared__ float4 crd[LL];   // x, y, z, |p|^2  (32 KB)
    int row0 = blockIdx.x * (8 * RPW);
    int base = row0 & ~(LL - 1);
    for (int t = threadIdx.x; t < LL; t += 512) {
        const float* p = X + (size_t)(base + t) * 12 + 3;   // atom 1 (CA)
        float x = p[0], y = p[1], z = p[2];
        crd[t] = make_float4(x, y, z, fmaf(x, x, fmaf(y, y, z * z)));
    }
    __syncthreads();

    int lane = threadIdx.x & 63;
    int gi0  = row0 + (threadIdx.x >> 6) * RPW;
    int i0   = gi0 - base;

    float qx[RPW], qy[RPW], qz[RPW], qn[RPW];
#pragma unroll
    for (int r = 0; r < RPW; ++r) {
        float4 ci = crd[i0 + r];
        qx[r] = ci.x; qy[r] = ci.y; qz[r] = ci.z; qn[r] = ci.w;
    }

    unsigned lst[RPW][PLM];
#pragma unroll
    for (int r = 0; r < RPW; ++r)
#pragma unroll
        for (int k = 0; k < PLM; ++k) lst[r][k] = 0xFFFFFFFFu;

#pragma unroll 2
    for (int s = 0; s < LL / 64; ++s) {
        int j = (s << 6) | lane;
        float4 c = crd[j];
#pragma unroll
        for (int r = 0; r < RPW; ++r) {
            float dot = fmaf(qx[r], c.x, fmaf(qy[r], c.y, qz[r] * c.z));
            float d2  = fmaf(-2.0f, dot, qn[r] + c.w);
            d2 = fmaxf(d2, 0.0f);
            unsigned cur = (__float_as_uint(d2) & 0xFFFFF800u) | (unsigned)j;
#pragma unroll
            for (int k = 0; k < PLM; ++k) {
                unsigned lo = min(lst[r][k], cur);
                cur = max(lst[r][k], cur);
                lst[r][k] = lo;
            }
        }
    }

#pragma unroll
    for (int r = 0; r < RPW; ++r) {
        int gi = gi0 + r;
        // extract the MTOP globally-smallest keys; lane t ends with the t-th
        unsigned mine = 0xFFFFFFFFu;
#pragma unroll
        for (int t = 0; t < MTOP; ++t) {
            unsigned m = lst[r][0];
#pragma unroll
            for (int off = 32; off >= 1; off >>= 1)
                m = min(m, (unsigned)__shfl_xor((int)m, off, 64));
            bool rem = (lst[r][0] == m);       // keys unique -> at most one lane
#pragma unroll
            for (int k = 0; k < PLM - 1; ++k) lst[r][k] = rem ? lst[r][k + 1] : lst[r][k];
            lst[r][PLM - 1] = rem ? 0xFFFFFFFFu : lst[r][PLM - 1];
            if (lane == t) mine = m;
        }

        // exact resort of the MTOP finalists by (D = sqrt(ref_d2 + eps), j)
        int jf = (int)(mine & (LL - 1));
        float4 cj = crd[jf];
        float D = sqrtf(__fadd_rn(ref_d2(qx[r], qy[r], qz[r], cj.x, cj.y, cj.z), 1e-6f));
        int rank = 0;
#pragma unroll
        for (int t = 0; t < MTOP; ++t) {
            float Dt = __shfl(D, t, 64);
            int   jt = __shfl(jf, t, 64);
            bool lt = (Dt < D) || (Dt == D && jt < jf);
            rank += lt ? 1 : 0;
        }

        if (lane < MTOP && rank < KNN) {
            int cg = base + jf;
            int e  = gi * KNN + rank;
            col_int[e]  = cg;
            out_row[e]  = (float)gi;
            out_col[e]  = (float)cg;
            int sr = seg[gi], sc = seg[cg];
            int ng = (isg[gi] | isg[cg]) ? 0 : 1;
            out_ctx[e]   = (sr == sc && ng) ? 1.0f : 0.0f;
            out_inter[e] = (sr != sc && ng) ? 1.0f : 0.0f;
        }
    }
}

// ---------------- kernel 2: node RBF features [N, 48] ----------------
__global__ __launch_bounds__(256) void node_kernel(const float* __restrict__ X,
                                                   float* __restrict__ out) {
    int n = blockIdx.x * 256 + threadIdx.x;
    if (n >= NN) return;
    const float* p = X + (size_t)n * 12;
    float d[3];
    d[0] = ref_dist(p[0], p[1],  p[2],  p[3], p[4], p[5]);
    d[1] = ref_dist(p[6], p[7],  p[8],  p[3], p[4], p[5]);
    d[2] = ref_dist(p[9], p[10], p[11], p[3], p[4], p[5]);
    float buf[48];
#pragma unroll
    for (int a = 0; a < 3; ++a)
#pragma unroll
        for (int t = 0; t < 16; ++t)
            buf[a * 16 + t] = rbf_val(d[a], t);
    float4* o = (float4*)(out + (size_t)n * 48);
#pragma unroll
    for (int q = 0; q < 12; ++q)
        o[q] = make_float4(buf[q * 4], buf[q * 4 + 1], buf[q * 4 + 2], buf[q * 4 + 3]);
}

// ---------------- kernel 3: edge RBF features [N*K, 64] ----------------
// One wave per edge; lane f: atom = f>>4, rbf center = f&15. Coalesced stores.
__global__ __launch_bounds__(256) void edge_kernel(const float* __restrict__ X,
                                                   const int* __restrict__ col_int,
                                                   float* __restrict__ out) {
    int gtid = blockIdx.x * 256 + threadIdx.x;
    int e = gtid >> 6;
    int f = gtid & 63;
    if (e >= NE) return;
    int row = e / KNN;
    int cg  = col_int[e];
    int atom = f >> 4, t = f & 15;
    const float* pr = X + (size_t)row * 12 + atom * 3;
    const float* pc = X + (size_t)cg * 12 + 3;
    float d = ref_dist(pr[0], pr[1], pr[2], pc[0], pc[1], pc[2]);
    out[(size_t)e * 64 + f] = rbf_val(d, t);
}

// ---------------- launcher ----------------
extern "C" void kernel_launch(void* const* d_in, const int* in_sizes, int n_in,
                              void* d_out, int out_size, void* d_ws, size_t ws_size,
                              hipStream_t stream) {
    const float* X       = (const float*)d_in[0];
    const int*   seg     = (const int*)d_in[1];
    const int*   isg_raw = (const int*)d_in[2];

    float* out = (float*)d_out;
    float* node_out  = out;                                   // [NN*48]
    float* edge_out  = out + (size_t)NN * 48;                 // [NE*64]
    float* row_out   = edge_out + (size_t)NE * 64;            // [NE]
    float* col_out   = row_out + NE;                          // [NE]
    float* ctx_out   = col_out + NE;                          // [NE]
    float* inter_out = ctx_out + NE;                          // [NE]

    int* isg     = (int*)d_ws;            // [NN] expanded is_global
    int* col_int = (int*)d_ws + NN;       // [NE] global col indices

    hipLaunchKernelGGL(expand_isg_kernel, dim3(32), dim3(256), 0, stream,
                       isg_raw, isg);
    hipLaunchKernelGGL(knn_kernel, dim3(NN / 32), dim3(512), 0, stream,
                       X, seg, isg, col_int, row_out, col_out, ctx_out, inter_out);
    hipLaunchKernelGGL(node_kernel, dim3(NN / 256), dim3(256), 0, stream,
                       X, node_out);
    hipLaunchKernelGGL(edge_kernel, dim3((NE * 64) / 256), dim3(256), 0, stream,
                       X, col_int, edge_out);
}

// Round 5
// 98.766 us; speedup vs baseline: 3.0552x; 1.0871x over previous
//
#include <hip/hip_runtime.h>
#include <cstdint>
#include <cstddef>

#define NN   32768
#define BATCH 16
#define LL   2048          // NN / BATCH
#define KNN  9
#define NE   (NN * KNN)    // 294912
#define PLM  5             // per-lane list size
#define MTOP 12            // global candidates extracted before exact resort
#define RPW  4             // rows per wave (scan amortization)

// ---------------- helpers ----------------

// Reference-exact squared distance (non-fused, fixed association).
__device__ __forceinline__ float ref_d2(float ax, float ay, float az,
                                        float bx, float by, float bz) {
    float dx = __fsub_rn(ax, bx);
    float dy = __fsub_rn(ay, by);
    float dz = __fsub_rn(az, bz);
    return __fadd_rn(__fadd_rn(__fmul_rn(dx, dx), __fmul_rn(dy, dy)),
                     __fmul_rn(dz, dz));
}

__device__ __forceinline__ float ref_dist(float ax, float ay, float az,
                                          float bx, float by, float bz) {
    return sqrtf(__fadd_rn(ref_d2(ax, ay, az, bx, by, bz), 1e-6f));
}

__device__ __forceinline__ float rbf_val(float d, int t) {
    // mu = linspace(0,20,16) -> t * (20/15); sigma = 20/16 = 1.25
    float mu = (float)t * (20.0f / 15.0f);
    float z = (d - mu) * 0.8f;   // /1.25
    return __expf(-z * z);
}

// Wave64 min-reduce, all-VALU (DPP), result broadcast via readlane(63).
// Sequence: row_shr 1,2,4,8 then row_bcast:15, row_bcast:31; invalid lanes
// take `old` = identity (0xFFFFFFFF), bound_ctrl=false.
#define DPP_MIN_STEP(x, ctrl)                                                  \
    {                                                                          \
        unsigned _t = (unsigned)__builtin_amdgcn_update_dpp(                   \
            (int)0xFFFFFFFF, (int)(x), (ctrl), 0xf, 0xf, false);               \
        (x) = min((x), _t);                                                    \
    }

__device__ __forceinline__ unsigned wave_min_u32(unsigned x) {
    DPP_MIN_STEP(x, 0x111);  // row_shr:1
    DPP_MIN_STEP(x, 0x112);  // row_shr:2
    DPP_MIN_STEP(x, 0x114);  // row_shr:4
    DPP_MIN_STEP(x, 0x118);  // row_shr:8
    DPP_MIN_STEP(x, 0x142);  // row_bcast:15
    DPP_MIN_STEP(x, 0x143);  // row_bcast:31
    return (unsigned)__builtin_amdgcn_readlane((int)x, 63);
}

// ---------------- kernel 0: normalize is_global to int32 ----------------
// Per-block dtype detection: packed random 0/1 bytes give a word>1 with
// P = 1 - 8^-256 (certain); int32 bools never do.
__global__ __launch_bounds__(256) void expand_isg_kernel(const int* __restrict__ raw,
                                                         int* __restrict__ out) {
    __shared__ int flag;
    if (threadIdx.x == 0) flag = 0;
    __syncthreads();
    unsigned v = (unsigned)raw[blockIdx.x * 256 + threadIdx.x];
    if (v > 1u) atomicOr(&flag, 1);
    __syncthreads();
    int t0 = blockIdx.x * 1024;
    if (flag) {
        const unsigned char* b = (const unsigned char*)raw;
        for (int t = threadIdx.x; t < 1024; t += 256) out[t0 + t] = b[t0 + t] ? 1 : 0;
    } else {
        for (int t = threadIdx.x; t < 1024; t += 256) out[t0 + t] = raw[t0 + t] ? 1 : 0;
    }
}

// ---------------- kernel 1: per-batch KNN + row/col/masks ----------------
// One wave handles RPW=4 consecutive rows; 512-thread block = 32 rows.
// Scan: one ds_read_b128 per candidate reused across 4 rows (regs);
//       approx d2 via (ni+nj-2*dot) fma; 21-bit truncated key | index;
//       mask-free min/max bubble insert into per-lane sorted top-5.
// Merge (per row): 12 rounds of DPP wave-min + branchless head removal.
// Resort (per row): exact (sqrt(ref_d2+eps), j) ranking via readlane.
__global__ __launch_bounds__(512) void knn_kernel(
    const float* __restrict__ X, const int* __restrict__ seg,
    const int* __restrict__ isg, int* __restrict__ col_int,
    float* __restrict__ out_row, float* __restrict__ out_col,
    float* __restrict__ out_ctx, float* __restrict__ out_inter)
{
    __shared__ float4 crd[LL];   // x, y, z, |p|^2  (32 KB)
    int row0 = blockIdx.x * (8 * RPW);
    int base = row0 & ~(LL - 1);
    for (int t = threadIdx.x; t < LL; t += 512) {
        const float* p = X + (size_t)(base + t) * 12 + 3;   // atom 1 (CA)
        float x = p[0], y = p[1], z = p[2];
        crd[t] = make_float4(x, y, z, fmaf(x, x, fmaf(y, y, z * z)));
    }
    __syncthreads();

    int lane = threadIdx.x & 63;
    int gi0  = row0 + (threadIdx.x >> 6) * RPW;
    int i0   = gi0 - base;

    float qx[RPW], qy[RPW], qz[RPW], qn[RPW];
#pragma unroll
    for (int r = 0; r < RPW; ++r) {
        float4 ci = crd[i0 + r];
        qx[r] = ci.x; qy[r] = ci.y; qz[r] = ci.z; qn[r] = ci.w;
    }

    unsigned lst[RPW][PLM];
#pragma unroll
    for (int r = 0; r < RPW; ++r)
#pragma unroll
        for (int k = 0; k < PLM; ++k) lst[r][k] = 0xFFFFFFFFu;

#pragma unroll 2
    for (int s = 0; s < LL / 64; ++s) {
        int j = (s << 6) | lane;
        float4 c = crd[j];
#pragma unroll
        for (int r = 0; r < RPW; ++r) {
            float dot = fmaf(qx[r], c.x, fmaf(qy[r], c.y, qz[r] * c.z));
            float d2  = fmaf(-2.0f, dot, qn[r] + c.w);
            // no fmax clamp: self-pair cancels to exactly +0 (identical fma
            // association as the |p|^2 precompute); nearest distinct pair has
            // d2 >> the ~1e-4 cancellation error, so sign is always correct.
            unsigned cur = (__float_as_uint(d2) & 0xFFFFF800u) | (unsigned)j;
#pragma unroll
            for (int k = 0; k < PLM; ++k) {
                unsigned lo = min(lst[r][k], cur);
                cur = max(lst[r][k], cur);
                lst[r][k] = lo;
            }
        }
    }

#pragma unroll
    for (int r = 0; r < RPW; ++r) {
        int gi = gi0 + r;
        // extract the MTOP globally-smallest keys; lane t ends with the t-th
        unsigned mine = 0xFFFFFFFFu;
#pragma unroll
        for (int t = 0; t < MTOP; ++t) {
            unsigned m = wave_min_u32(lst[r][0]);     // uniform scalar
            bool rem = (lst[r][0] == m);              // keys unique -> ≤1 lane
#pragma unroll
            for (int k = 0; k < PLM - 1; ++k) lst[r][k] = rem ? lst[r][k + 1] : lst[r][k];
            lst[r][PLM - 1] = rem ? 0xFFFFFFFFu : lst[r][PLM - 1];
            mine = (lane == t) ? m : mine;
        }

        // exact resort of the MTOP finalists by (D = sqrt(ref_d2 + eps), j)
        int jf = (int)(mine & (LL - 1));
        float4 cj = crd[jf];
        float D = sqrtf(__fadd_rn(ref_d2(qx[r], qy[r], qz[r], cj.x, cj.y, cj.z), 1e-6f));
        int rank = 0;
#pragma unroll
        for (int t = 0; t < MTOP; ++t) {
            float Dt = __int_as_float(__builtin_amdgcn_readlane(__float_as_int(D), t));
            int   jt = __builtin_amdgcn_readlane(jf, t);
            bool lt = (Dt < D) || (Dt == D && jt < jf);
            rank += lt ? 1 : 0;
        }

        if (lane < MTOP && rank < KNN) {
            int cg = base + jf;
            int e  = gi * KNN + rank;
            col_int[e]  = cg;
            out_row[e]  = (float)gi;
            out_col[e]  = (float)cg;
            int sr = seg[gi], sc = seg[cg];
            int ng = (isg[gi] | isg[cg]) ? 0 : 1;
            out_ctx[e]   = (sr == sc && ng) ? 1.0f : 0.0f;
            out_inter[e] = (sr != sc && ng) ? 1.0f : 0.0f;
        }
    }
}

// ---------------- kernel 2: node RBF features [N, 48] ----------------
__global__ __launch_bounds__(256) void node_kernel(const float* __restrict__ X,
                                                   float* __restrict__ out) {
    int n = blockIdx.x * 256 + threadIdx.x;
    if (n >= NN) return;
    const float* p = X + (size_t)n * 12;
    float d[3];
    d[0] = ref_dist(p[0], p[1],  p[2],  p[3], p[4], p[5]);
    d[1] = ref_dist(p[6], p[7],  p[8],  p[3], p[4], p[5]);
    d[2] = ref_dist(p[9], p[10], p[11], p[3], p[4], p[5]);
    float buf[48];
#pragma unroll
    for (int a = 0; a < 3; ++a)
#pragma unroll
        for (int t = 0; t < 16; ++t)
            buf[a * 16 + t] = rbf_val(d[a], t);
    float4* o = (float4*)(out + (size_t)n * 48);
#pragma unroll
    for (int q = 0; q < 12; ++q)
        o[q] = make_float4(buf[q * 4], buf[q * 4 + 1], buf[q * 4 + 2], buf[q * 4 + 3]);
}

// ---------------- kernel 3: edge RBF features [N*K, 64] ----------------
// One wave per edge; lane f: atom = f>>4, rbf center = f&15. Coalesced stores.
__global__ __launch_bounds__(256) void edge_kernel(const float* __restrict__ X,
                                                   const int* __restrict__ col_int,
                                                   float* __restrict__ out) {
    int gtid = blockIdx.x * 256 + threadIdx.x;
    int e = gtid >> 6;
    int f = gtid & 63;
    if (e >= NE) return;
    int row = e / KNN;
    int cg  = col_int[e];
    int atom = f >> 4, t = f & 15;
    const float* pr = X + (size_t)row * 12 + atom * 3;
    const float* pc = X + (size_t)cg * 12 + 3;
    float d = ref_dist(pr[0], pr[1], pr[2], pc[0], pc[1], pc[2]);
    out[(size_t)e * 64 + f] = rbf_val(d, t);
}

// ---------------- launcher ----------------
extern "C" void kernel_launch(void* const* d_in, const int* in_sizes, int n_in,
                              void* d_out, int out_size, void* d_ws, size_t ws_size,
                              hipStream_t stream) {
    const float* X       = (const float*)d_in[0];
    const int*   seg     = (const int*)d_in[1];
    const int*   isg_raw = (const int*)d_in[2];

    float* out = (float*)d_out;
    float* node_out  = out;                                   // [NN*48]
    float* edge_out  = out + (size_t)NN * 48;                 // [NE*64]
    float* row_out   = edge_out + (size_t)NE * 64;            // [NE]
    float* col_out   = row_out + NE;                          // [NE]
    float* ctx_out   = col_out + NE;                          // [NE]
    float* inter_out = ctx_out + NE;                          // [NE]

    int* isg     = (int*)d_ws;            // [NN] expanded is_global
    int* col_int = (int*)d_ws + NN;       // [NE] global col indices

    hipLaunchKernelGGL(expand_isg_kernel, dim3(32), dim3(256), 0, stream,
                       isg_raw, isg);
    hipLaunchKernelGGL(knn_kernel, dim3(NN / 32), dim3(512), 0, stream,
                       X, seg, isg, col_int, row_out, col_out, ctx_out, inter_out);
    hipLaunchKernelGGL(node_kernel, dim3(NN / 256), dim3(256), 0, stream,
                       X, node_out);
    hipLaunchKernelGGL(edge_kernel, dim3((NE * 64) / 256), dim3(256), 0, stream,
                       X, col_int, edge_out);
}

// Round 6
// 62.196 us; speedup vs baseline: 4.8516x; 1.5880x over previous
//
#include <hip/hip_runtime.h>
#include <cstdint>
#include <cstddef>

#define NN   32768
#define BATCH 16
#define LL   2048          // NN / BATCH
#define KNN  9
#define NE   (NN * KNN)    // 294912
#define PLM  5             // per-lane list size
#define MTOP 12            // global candidates extracted before exact resort
#define RPW  4             // rows per wave
#define TPB  512           // threads per block (8 waves)
#define ROWS_PB 32         // rows per block = (TPB/64) * RPW

// ---------------- helpers ----------------

// Reference-exact squared distance (non-fused, fixed association).
__device__ __forceinline__ float ref_d2(float ax, float ay, float az,
                                        float bx, float by, float bz) {
    float dx = __fsub_rn(ax, bx);
    float dy = __fsub_rn(ay, by);
    float dz = __fsub_rn(az, bz);
    return __fadd_rn(__fadd_rn(__fmul_rn(dx, dx), __fmul_rn(dy, dy)),
                     __fmul_rn(dz, dz));
}

__device__ __forceinline__ float ref_dist(float ax, float ay, float az,
                                          float bx, float by, float bz) {
    return sqrtf(__fadd_rn(ref_d2(ax, ay, az, bx, by, bz), 1e-6f));
}

__device__ __forceinline__ float rbf_val(float d, int t) {
    // mu = linspace(0,20,16) -> t * (20/15); sigma = 20/16 = 1.25
    float mu = (float)t * (20.0f / 15.0f);
    float z = (d - mu) * 0.8f;   // /1.25
    return __expf(-z * z);
}

// Wave64 min-reduce, all-VALU (DPP), result broadcast via readlane(63).
#define DPP_MIN_STEP(x, ctrl)                                                  \
    {                                                                          \
        unsigned _t = (unsigned)__builtin_amdgcn_update_dpp(                   \
            (int)0xFFFFFFFF, (int)(x), (ctrl), 0xf, 0xf, false);               \
        (x) = min((x), _t);                                                    \
    }

__device__ __forceinline__ unsigned wave_min_u32(unsigned x) {
    DPP_MIN_STEP(x, 0x111);  // row_shr:1
    DPP_MIN_STEP(x, 0x112);  // row_shr:2
    DPP_MIN_STEP(x, 0x114);  // row_shr:4
    DPP_MIN_STEP(x, 0x118);  // row_shr:8
    DPP_MIN_STEP(x, 0x142);  // row_bcast:15
    DPP_MIN_STEP(x, 0x143);  // row_bcast:31
    return (unsigned)__builtin_amdgcn_readlane((int)x, 63);
}

// ---------------- single fused kernel ----------------
// Per block: 32 rows of one batch. Phases:
//  A) stage CA coords (float4 w/ |p|^2) + packed seg/isg codes into LDS
//     (with per-block is_global byte-vs-int layout detection)
//  B) scan: branchless per-lane top-5 of 21-bit-truncated-d2|idx keys,
//     one LDS float4 read reused across 4 rows
//  C) per row: 12 DPP wave-min extractions + exact (sqrt,j) resort,
//     write row/col/ctx/inter, stash finalist idx in LDS
//  D) edge RBF features: 36 coalesced 256B store passes per wave
//  E) node RBF features: contiguous 192-float span per wave
__global__ __launch_bounds__(TPB, 8) void fused_kernel(
    const float* __restrict__ X, const int* __restrict__ seg,
    const int* __restrict__ isg_raw,
    float* __restrict__ node_out, float* __restrict__ edge_out,
    float* __restrict__ out_row, float* __restrict__ out_col,
    float* __restrict__ out_ctx, float* __restrict__ out_inter)
{
    __shared__ float4 crd[LL];            // 32 KB: x, y, z, |p|^2
    __shared__ unsigned char code[LL];    // 2 KB: seg | (isg<<2)
    __shared__ int colsL[TPB / 64][RPW][KNN];  // finalist local idx per rank
    __shared__ int flag;

    int tid  = threadIdx.x;
    int row0 = blockIdx.x * ROWS_PB;
    int base = row0 & ~(LL - 1);

    // --- A: detect is_global layout (bytes vs int32) for this batch ---
    if (tid == 0) flag = 0;
    __syncthreads();
    {
        // 512 ints cover the batch's byte-layout region [base/4, base/4+512).
        // Packed 0/1 bytes: P(word<=1) = 1/8 per word -> detection certain.
        // int32 layout: these words are 0/1 -> flag stays 0.
        unsigned v = (unsigned)isg_raw[(base >> 2) + tid];
        if (v > 1u) atomicOr(&flag, 1);
    }
    __syncthreads();
    bool as_bytes = (flag != 0);
    for (int t = tid; t < LL; t += TPB) {
        const float* p = X + (size_t)(base + t) * 12 + 3;   // atom 1 (CA)
        float x = p[0], y = p[1], z = p[2];
        crd[t] = make_float4(x, y, z, fmaf(x, x, fmaf(y, y, z * z)));
        int ig = as_bytes ? (int)((const unsigned char*)isg_raw)[base + t]
                          : isg_raw[base + t];
        code[t] = (unsigned char)((seg[base + t] & 3) | (ig ? 4 : 0));
    }
    __syncthreads();

    int lane = tid & 63;
    int warp = tid >> 6;
    int gi0  = row0 + warp * RPW;
    int i0   = gi0 - base;

    float qx[RPW], qy[RPW], qz[RPW], qn[RPW];
#pragma unroll
    for (int r = 0; r < RPW; ++r) {
        float4 ci = crd[i0 + r];
        qx[r] = ci.x; qy[r] = ci.y; qz[r] = ci.z; qn[r] = ci.w;
    }

    // --- B: scan ---
    unsigned lst[RPW][PLM];
#pragma unroll
    for (int r = 0; r < RPW; ++r)
#pragma unroll
        for (int k = 0; k < PLM; ++k) lst[r][k] = 0xFFFFFFFFu;

#pragma unroll 2
    for (int s = 0; s < LL / 64; ++s) {
        int j = (s << 6) | lane;
        float4 c = crd[j];
#pragma unroll
        for (int r = 0; r < RPW; ++r) {
            float dot = fmaf(qx[r], c.x, fmaf(qy[r], c.y, qz[r] * c.z));
            float d2  = fmaf(-2.0f, dot, qn[r] + c.w);
            unsigned cur = (__float_as_uint(d2) & 0xFFFFF800u) | (unsigned)j;
#pragma unroll
            for (int k = 0; k < PLM; ++k) {
                unsigned lo = min(lst[r][k], cur);
                cur = max(lst[r][k], cur);
                lst[r][k] = lo;
            }
        }
    }

    // --- C: extraction + exact resort + graph outputs ---
#pragma unroll
    for (int r = 0; r < RPW; ++r) {
        int gi = gi0 + r;
        unsigned mine = 0xFFFFFFFFu;
#pragma unroll
        for (int t = 0; t < MTOP; ++t) {
            unsigned m = wave_min_u32(lst[r][0]);     // uniform scalar
            bool rem = (lst[r][0] == m);              // keys unique -> <=1 lane
#pragma unroll
            for (int k = 0; k < PLM - 1; ++k) lst[r][k] = rem ? lst[r][k + 1] : lst[r][k];
            lst[r][PLM - 1] = rem ? 0xFFFFFFFFu : lst[r][PLM - 1];
            mine = (lane == t) ? m : mine;
        }

        int jf = (int)(mine & (LL - 1));
        float4 cj = crd[jf];
        float D = sqrtf(__fadd_rn(ref_d2(qx[r], qy[r], qz[r], cj.x, cj.y, cj.z), 1e-6f));
        int rank = 0;
#pragma unroll
        for (int t = 0; t < MTOP; ++t) {
            float Dt = __int_as_float(__builtin_amdgcn_readlane(__float_as_int(D), t));
            int   jt = __builtin_amdgcn_readlane(jf, t);
            bool lt = (Dt < D) || (Dt == D && jt < jf);
            rank += lt ? 1 : 0;
        }

        if (lane < MTOP && rank < KNN) {
            int cg = base + jf;
            int e  = gi * KNN + rank;
            out_row[e] = (float)gi;
            out_col[e] = (float)cg;
            int cr = code[gi - base], cc = code[jf];
            int ng = ((cr | cc) & 4) ? 0 : 1;
            int sr = cr & 3, sc = cc & 3;
            out_ctx[e]   = (sr == sc && ng) ? 1.0f : 0.0f;
            out_inter[e] = (sr != sc && ng) ? 1.0f : 0.0f;
            colsL[warp][r][rank] = jf;
        }
    }

    // --- D: edge RBF features (wave-local; cols from LDS, col-CA from crd) ---
    int atom = lane >> 4, tt = lane & 15;
    float rxa[RPW][3];
#pragma unroll
    for (int r = 0; r < RPW; ++r) {
        const float* pr = X + (size_t)(gi0 + r) * 12 + atom * 3;
        rxa[r][0] = pr[0]; rxa[r][1] = pr[1]; rxa[r][2] = pr[2];
    }
#pragma unroll
    for (int e = 0; e < RPW * KNN; ++e) {
        int r = e / KNN, q = e - r * KNN;
        int jf = colsL[warp][r][q];       // broadcast LDS read
        float4 cj = crd[jf];              // broadcast LDS read
        float d = ref_dist(rxa[r][0], rxa[r][1], rxa[r][2], cj.x, cj.y, cj.z);
        edge_out[((size_t)(gi0 + r) * KNN + q) * 64 + lane] = rbf_val(d, tt);
    }

    // --- E: node RBF features (contiguous per-wave span) ---
#pragma unroll
    for (int s = 0; s < 3; ++s) {
        int idx = lane + 64 * s;          // 0..191 over 4 rows x 48 feats
        int r   = idx / 48, c = idx - r * 48;
        int a   = c >> 4, tc = c & 15;
        int gi  = gi0 + r;
        int asrc = (a == 0) ? 0 : a + 1;  // atoms 0, 2, 3 vs CA
        const float* pa = X + (size_t)gi * 12 + asrc * 3;
        float4 ca = crd[gi - base];
        float d = ref_dist(pa[0], pa[1], pa[2], ca.x, ca.y, ca.z);
        node_out[(size_t)gi * 48 + c] = rbf_val(d, tc);
    }
}

// ---------------- launcher ----------------
extern "C" void kernel_launch(void* const* d_in, const int* in_sizes, int n_in,
                              void* d_out, int out_size, void* d_ws, size_t ws_size,
                              hipStream_t stream) {
    const float* X       = (const float*)d_in[0];
    const int*   seg     = (const int*)d_in[1];
    const int*   isg_raw = (const int*)d_in[2];

    float* out = (float*)d_out;
    float* node_out  = out;                                   // [NN*48]
    float* edge_out  = out + (size_t)NN * 48;                 // [NE*64]
    float* row_out   = edge_out + (size_t)NE * 64;            // [NE]
    float* col_out   = row_out + NE;                          // [NE]
    float* ctx_out   = col_out + NE;                          // [NE]
    float* inter_out = ctx_out + NE;                          // [NE]

    hipLaunchKernelGGL(fused_kernel, dim3(NN / ROWS_PB), dim3(TPB), 0, stream,
                       X, seg, isg_raw,
                       node_out, edge_out, row_out, col_out, ctx_out, inter_out);
}

// Round 7
// 60.743 us; speedup vs baseline: 4.9677x; 1.0239x over previous
//
#include <hip/hip_runtime.h>
#include <cstdint>
#include <cstddef>

#define NN   32768
#define BATCH 16
#define LL   2048          // NN / BATCH
#define KNN  9
#define NE   (NN * KNN)    // 294912
#define PLM  5             // per-lane list size
#define MTOP 12            // global candidates extracted before exact resort
#define RPW  2             // rows per wave
#define TPB  1024          // threads per block (16 waves)
#define ROWS_PB ((TPB / 64) * RPW)   // 32 rows per block

// ---------------- helpers ----------------

// Reference-exact squared distance (non-fused, fixed association).
__device__ __forceinline__ float ref_d2(float ax, float ay, float az,
                                        float bx, float by, float bz) {
    float dx = __fsub_rn(ax, bx);
    float dy = __fsub_rn(ay, by);
    float dz = __fsub_rn(az, bz);
    return __fadd_rn(__fadd_rn(__fmul_rn(dx, dx), __fmul_rn(dy, dy)),
                     __fmul_rn(dz, dz));
}

__device__ __forceinline__ float ref_dist(float ax, float ay, float az,
                                          float bx, float by, float bz) {
    return sqrtf(__fadd_rn(ref_d2(ax, ay, az, bx, by, bz), 1e-6f));
}

// One DPP row_shr min step (within rows of 16); invalid lanes take identity.
__device__ __forceinline__ unsigned dpp_min16_4(unsigned x) {
    unsigned t;
    t = (unsigned)__builtin_amdgcn_update_dpp((int)0xFFFFFFFF, (int)x, 0x111, 0xf, 0xf, false);
    x = min(x, t);
    t = (unsigned)__builtin_amdgcn_update_dpp((int)0xFFFFFFFF, (int)x, 0x112, 0xf, 0xf, false);
    x = min(x, t);
    t = (unsigned)__builtin_amdgcn_update_dpp((int)0xFFFFFFFF, (int)x, 0x114, 0xf, 0xf, false);
    x = min(x, t);
    t = (unsigned)__builtin_amdgcn_update_dpp((int)0xFFFFFFFF, (int)x, 0x118, 0xf, 0xf, false);
    x = min(x, t);
    return x;   // lane 15 of each 16-group holds that group's min
}

__device__ __forceinline__ unsigned gather_min(unsigned a) {
    unsigned m0 = min((unsigned)__builtin_amdgcn_readlane((int)a, 15),
                      (unsigned)__builtin_amdgcn_readlane((int)a, 31));
    unsigned m1 = min((unsigned)__builtin_amdgcn_readlane((int)a, 47),
                      (unsigned)__builtin_amdgcn_readlane((int)a, 63));
    return min(m0, m1);   // uniform (SALU)
}

// ---------------- single fused kernel ----------------
//  A) stage CA coords (float4 w/ |p|^2), row atoms, packed seg/isg codes
//  B) scan: branchless per-lane top-5 of 21-bit-truncated-d2|idx keys
//  C) per row: 12 extraction rounds (DPP16 + readlane + SALU min) + exact resort
//  D) edge RBF features: float4 stores, 6 passes, atoms from LDS
//  E) node RBF features: single float4 pass
__global__ __launch_bounds__(TPB, 8) void fused_kernel(
    const float* __restrict__ X, const int* __restrict__ seg,
    const int* __restrict__ isg_raw,
    float* __restrict__ node_out, float* __restrict__ edge_out,
    float* __restrict__ out_row, float* __restrict__ out_col,
    float* __restrict__ out_ctx, float* __restrict__ out_inter)
{
    __shared__ float4 crd[LL];                 // 32 KB: x, y, z, |p|^2
    __shared__ float rowatoms[ROWS_PB * 12];   // 1.5 KB: this block's 4-atom rows
    __shared__ unsigned char code[LL];         // 2 KB: seg | (isg<<2)
    __shared__ int colsL[TPB / 64][RPW][KNN];  // finalist local idx per rank
    __shared__ int flag;

    int tid  = threadIdx.x;
    int row0 = blockIdx.x * ROWS_PB;
    int base = row0 & ~(LL - 1);

    // --- A: is_global layout detection (bytes vs int32), staging ---
    if (tid == 0) flag = 0;
    __syncthreads();
    if (tid < 512) {
        // 512 ints cover the batch's byte-layout region; packed 0/1 bytes give
        // a word>1 with P = 1-8^-512 (certain); int32 bools never do.
        unsigned v = (unsigned)isg_raw[(base >> 2) + tid];
        if (v > 1u) atomicOr(&flag, 1);
    }
    if (tid < ROWS_PB * 12)
        rowatoms[tid] = X[(size_t)row0 * 12 + tid];
    __syncthreads();
    bool as_bytes = (flag != 0);
    for (int t = tid; t < LL; t += TPB) {
        const float* p = X + (size_t)(base + t) * 12 + 3;   // atom 1 (CA)
        float x = p[0], y = p[1], z = p[2];
        crd[t] = make_float4(x, y, z, fmaf(x, x, fmaf(y, y, z * z)));
        int ig = as_bytes ? (int)((const unsigned char*)isg_raw)[base + t]
                          : isg_raw[base + t];
        code[t] = (unsigned char)((seg[base + t] & 3) | (ig ? 4 : 0));
    }
    __syncthreads();

    int lane = tid & 63;
    int warp = tid >> 6;
    int gi0  = row0 + warp * RPW;
    int i0   = gi0 - base;

    float qx[RPW], qy[RPW], qz[RPW], qn[RPW];
#pragma unroll
    for (int r = 0; r < RPW; ++r) {
        float4 ci = crd[i0 + r];
        qx[r] = ci.x; qy[r] = ci.y; qz[r] = ci.z; qn[r] = ci.w;
    }

    // --- B: scan (key math bit-identical to prior passing rounds) ---
    unsigned lst[RPW][PLM];
#pragma unroll
    for (int r = 0; r < RPW; ++r)
#pragma unroll
        for (int k = 0; k < PLM; ++k) lst[r][k] = 0xFFFFFFFFu;

#pragma unroll 4
    for (int s = 0; s < LL / 64; ++s) {
        int j = (s << 6) | lane;
        float4 c = crd[j];
#pragma unroll
        for (int r = 0; r < RPW; ++r) {
            float dot = fmaf(qx[r], c.x, fmaf(qy[r], c.y, qz[r] * c.z));
            float d2  = fmaf(-2.0f, dot, qn[r] + c.w);   // self-pair == exact +0
            unsigned cur = (__float_as_uint(d2) & 0xFFFFF800u) | (unsigned)j;
#pragma unroll
            for (int k = 0; k < PLM; ++k) {
                unsigned lo = min(lst[r][k], cur);
                cur = max(lst[r][k], cur);
                lst[r][k] = lo;
            }
        }
    }

    // --- C: extraction (rows interleaved for ILP) ---
    unsigned mine[RPW];
#pragma unroll
    for (int r = 0; r < RPW; ++r) mine[r] = 0xFFFFFFFFu;

#pragma unroll
    for (int t = 0; t < MTOP; ++t) {
        unsigned a0 = dpp_min16_4(lst[0][0]);
        unsigned a1 = dpp_min16_4(lst[1][0]);
        unsigned m0 = gather_min(a0);
        unsigned m1 = gather_min(a1);
        bool rem0 = (lst[0][0] == m0);
        bool rem1 = (lst[1][0] == m1);
#pragma unroll
        for (int k = 0; k < PLM - 1; ++k) {
            lst[0][k] = rem0 ? lst[0][k + 1] : lst[0][k];
            lst[1][k] = rem1 ? lst[1][k + 1] : lst[1][k];
        }
        lst[0][PLM - 1] = rem0 ? 0xFFFFFFFFu : lst[0][PLM - 1];
        lst[1][PLM - 1] = rem1 ? 0xFFFFFFFFu : lst[1][PLM - 1];
        mine[0] = (lane == t) ? m0 : mine[0];
        mine[1] = (lane == t) ? m1 : mine[1];
    }

    // exact resort + graph outputs, per row
#pragma unroll
    for (int r = 0; r < RPW; ++r) {
        int gi = gi0 + r;
        int jf = (int)(mine[r] & (LL - 1));
        float4 cj = crd[jf];
        float D = sqrtf(__fadd_rn(ref_d2(qx[r], qy[r], qz[r], cj.x, cj.y, cj.z), 1e-6f));
        int rank = 0;
#pragma unroll
        for (int t = 0; t < MTOP; ++t) {
            float Dt = __int_as_float(__builtin_amdgcn_readlane(__float_as_int(D), t));
            int   jt = __builtin_amdgcn_readlane(jf, t);
            bool lt = (Dt < D) || (Dt == D && jt < jf);
            rank += lt ? 1 : 0;
        }
        if (lane < MTOP && rank < KNN) {
            int cg = base + jf;
            int e  = gi * KNN + rank;
            out_row[e] = (float)gi;
            out_col[e] = (float)cg;
            int cr = code[gi - base], cc = code[jf];
            int ng = ((cr | cc) & 4) ? 0 : 1;
            int sr = cr & 3, sc = cc & 3;
            out_ctx[e]   = (sr == sc && ng) ? 1.0f : 0.0f;
            out_inter[e] = (sr != sc && ng) ? 1.0f : 0.0f;
            colsL[warp][r][rank] = jf;
        }
    }

    // --- D: edge RBF features, float4 stores ---
    // pass p: 3 edges (slot sE = lane>>4 < 3), chunk g = lane&15 covers
    // feats [4g, 4g+3]: atom = g>>2, t = (g&3)*4 + k.
    {
        int g = lane & 15, sE = lane >> 4;
        int atomE = g >> 2;
        float zk[4];
        float tbE = (float)((g & 3) * 4);
#pragma unroll
        for (int k = 0; k < 4; ++k)
            zk[k] = -(tbE + (float)k) * (20.0f / 15.0f) * 0.8f;  // -mu*0.8
        int rA = warp * RPW;
        if (sE < 3) {
#pragma unroll
            for (int p = 0; p < 3 * RPW; ++p) {
                int r = p / 3;                    // static after unroll
                int q = (p % 3) * 3 + sE;         // 0..8
                int jf = colsL[warp][r][q];
                float4 cj = crd[jf];
                const float* ra = &rowatoms[(rA + r) * 12 + atomE * 3];
                float d = ref_dist(ra[0], ra[1], ra[2], cj.x, cj.y, cj.z);
                float4 v;
                float z0 = fmaf(d, 0.8f, zk[0]); v.x = __expf(-z0 * z0);
                float z1 = fmaf(d, 0.8f, zk[1]); v.y = __expf(-z1 * z1);
                float z2 = fmaf(d, 0.8f, zk[2]); v.z = __expf(-z2 * z2);
                float z3 = fmaf(d, 0.8f, zk[3]); v.w = __expf(-z3 * z3);
                *(float4*)(edge_out + ((size_t)(gi0 + r) * KNN + q) * 64 + g * 4) = v;
            }
        }
    }

    // --- E: node RBF features, single float4 pass ---
    // lane < 24: row rn = lane/12, chunk c4 = lane%12 covers feats [4c4, 4c4+3]
    if (lane < 24) {
        int rn = lane / 12;
        int c4 = lane - rn * 12;
        int aN = c4 >> 2;
        int asrc = (aN == 0) ? 0 : aN + 1;        // atoms 0, 2, 3 vs CA
        float tbN = (float)((c4 & 3) * 4);
        float zn[4];
#pragma unroll
        for (int k = 0; k < 4; ++k)
            zn[k] = -(tbN + (float)k) * (20.0f / 15.0f) * 0.8f;
        const float* ra = &rowatoms[(warp * RPW + rn) * 12 + asrc * 3];
        float4 ca = crd[i0 + rn];
        float d = ref_dist(ra[0], ra[1], ra[2], ca.x, ca.y, ca.z);
        float4 v;
        float z0 = fmaf(d, 0.8f, zn[0]); v.x = __expf(-z0 * z0);
        float z1 = fmaf(d, 0.8f, zn[1]); v.y = __expf(-z1 * z1);
        float z2 = fmaf(d, 0.8f, zn[2]); v.z = __expf(-z2 * z2);
        float z3 = fmaf(d, 0.8f, zn[3]); v.w = __expf(-z3 * z3);
        *(float4*)(node_out + (size_t)(gi0 + rn) * 48 + c4 * 4) = v;
    }
}

// ---------------- launcher ----------------
extern "C" void kernel_launch(void* const* d_in, const int* in_sizes, int n_in,
                              void* d_out, int out_size, void* d_ws, size_t ws_size,
                              hipStream_t stream) {
    const float* X       = (const float*)d_in[0];
    const int*   seg     = (const int*)d_in[1];
    const int*   isg_raw = (const int*)d_in[2];

    float* out = (float*)d_out;
    float* node_out  = out;                                   // [NN*48]
    float* edge_out  = out + (size_t)NN * 48;                 // [NE*64]
    float* row_out   = edge_out + (size_t)NE * 64;            // [NE]
    float* col_out   = row_out + NE;                          // [NE]
    float* ctx_out   = col_out + NE;                          // [NE]
    float* inter_out = ctx_out + NE;                          // [NE]

    hipLaunchKernelGGL(fused_kernel, dim3(NN / ROWS_PB), dim3(TPB), 0, stream,
                       X, seg, isg_raw,
                       node_out, edge_out, row_out, col_out, ctx_out, inter_out);
}

// Round 8
// 58.242 us; speedup vs baseline: 5.1810x; 1.0429x over previous
//
#include <hip/hip_runtime.h>
#include <cstdint>
#include <cstddef>

#define NN   32768
#define BATCH 16
#define LL   2048          // NN / BATCH
#define KNN  9
#define NE   (NN * KNN)    // 294912
#define PLM  5             // per-lane list size
#define MTOP 12            // global candidates extracted before exact resort
#define RPW  4             // rows per wave
#define TPB  1024          // threads per block (16 waves)
#define ROWS_PB ((TPB / 64) * RPW)   // 64 rows per block -> grid = 512

// ---------------- helpers ----------------

// Reference-exact squared distance (non-fused, fixed association) — used only
// in the exact resort and feature phases, unchanged across rounds.
__device__ __forceinline__ float ref_d2(float ax, float ay, float az,
                                        float bx, float by, float bz) {
    float dx = __fsub_rn(ax, bx);
    float dy = __fsub_rn(ay, by);
    float dz = __fsub_rn(az, bz);
    return __fadd_rn(__fadd_rn(__fmul_rn(dx, dx), __fmul_rn(dy, dy)),
                     __fmul_rn(dz, dz));
}

__device__ __forceinline__ float ref_dist(float ax, float ay, float az,
                                          float bx, float by, float bz) {
    return sqrtf(__fadd_rn(ref_d2(ax, ay, az, bx, by, bz), 1e-6f));
}

// One DPP row_shr min chain (within rows of 16); invalid lanes take identity.
__device__ __forceinline__ unsigned dpp_min16_4(unsigned x) {
    unsigned t;
    t = (unsigned)__builtin_amdgcn_update_dpp((int)0xFFFFFFFF, (int)x, 0x111, 0xf, 0xf, false);
    x = min(x, t);
    t = (unsigned)__builtin_amdgcn_update_dpp((int)0xFFFFFFFF, (int)x, 0x112, 0xf, 0xf, false);
    x = min(x, t);
    t = (unsigned)__builtin_amdgcn_update_dpp((int)0xFFFFFFFF, (int)x, 0x114, 0xf, 0xf, false);
    x = min(x, t);
    t = (unsigned)__builtin_amdgcn_update_dpp((int)0xFFFFFFFF, (int)x, 0x118, 0xf, 0xf, false);
    x = min(x, t);
    return x;   // lane 15 of each 16-group holds that group's min
}

__device__ __forceinline__ unsigned gather_min(unsigned a) {
    unsigned m0 = min((unsigned)__builtin_amdgcn_readlane((int)a, 15),
                      (unsigned)__builtin_amdgcn_readlane((int)a, 31));
    unsigned m1 = min((unsigned)__builtin_amdgcn_readlane((int)a, 47),
                      (unsigned)__builtin_amdgcn_readlane((int)a, 63));
    return min(m0, m1);   // uniform (SALU)
}

// ---------------- single fused kernel ----------------
//  A) stage CA coords (float4 w/ |p|^2), row atoms, packed seg/isg codes
//  B) scan: per-lane top-5 of truncated-d2|idx keys; d2 via hoisted
//     (-2q)-fma chain + clamp; one ds_read_b128 shared across 4 rows
//  C) extraction: 12 rounds, 4 row-chains interleaved (DPP16+readlane+SALU)
//  D) exact resort per row + graph outputs
//  E) edge RBF features: float4 stores, 12 passes
//  F) node RBF features: single float4 pass (lane < 48)
__global__ __launch_bounds__(TPB, 8) void fused_kernel(
    const float* __restrict__ X, const int* __restrict__ seg,
    const int* __restrict__ isg_raw,
    float* __restrict__ node_out, float* __restrict__ edge_out,
    float* __restrict__ out_row, float* __restrict__ out_col,
    float* __restrict__ out_ctx, float* __restrict__ out_inter)
{
    __shared__ float4 crd[LL];                 // 32 KB: x, y, z, |p|^2
    __shared__ float rowatoms[ROWS_PB * 12];   // 3 KB: this block's 4-atom rows
    __shared__ unsigned char code[LL];         // 2 KB: seg | (isg<<2)
    __shared__ int colsL[TPB / 64][RPW][KNN];  // finalist local idx per rank
    __shared__ int flag;

    int tid  = threadIdx.x;
    int row0 = blockIdx.x * ROWS_PB;
    int base = row0 & ~(LL - 1);

    // --- A: is_global layout detection (bytes vs int32), staging ---
    if (tid == 0) flag = 0;
    __syncthreads();
    if (tid < 512) {
        // 512 ints cover the batch's byte-layout region; packed 0/1 bytes give
        // a word>1 with P = 1-8^-512 (certain); int32 bools never do.
        unsigned v = (unsigned)isg_raw[(base >> 2) + tid];
        if (v > 1u) atomicOr(&flag, 1);
    }
    if (tid < ROWS_PB * 12)
        rowatoms[tid] = X[(size_t)row0 * 12 + tid];
    __syncthreads();
    bool as_bytes = (flag != 0);
    for (int t = tid; t < LL; t += TPB) {
        const float* p = X + (size_t)(base + t) * 12 + 3;   // atom 1 (CA)
        float x = p[0], y = p[1], z = p[2];
        crd[t] = make_float4(x, y, z, fmaf(x, x, fmaf(y, y, z * z)));
        int ig = as_bytes ? (int)((const unsigned char*)isg_raw)[base + t]
                          : isg_raw[base + t];
        code[t] = (unsigned char)((seg[base + t] & 3) | (ig ? 4 : 0));
    }
    __syncthreads();

    int lane = tid & 63;
    int warp = tid >> 6;
    int gi0  = row0 + warp * RPW;
    int i0   = gi0 - base;

    // hoisted per-row scan constants: (-2x, -2y, -2z, |p|^2)
    float qx2[RPW], qy2[RPW], qz2[RPW], qn[RPW];
#pragma unroll
    for (int r = 0; r < RPW; ++r) {
        float4 ci = crd[i0 + r];
        qx2[r] = -2.0f * ci.x; qy2[r] = -2.0f * ci.y; qz2[r] = -2.0f * ci.z;
        qn[r] = ci.w;
    }

    // --- B: scan ---
    unsigned lst[RPW][PLM];
#pragma unroll
    for (int r = 0; r < RPW; ++r)
#pragma unroll
        for (int k = 0; k < PLM; ++k) lst[r][k] = 0xFFFFFFFFu;

#pragma unroll 8
    for (int s = 0; s < LL / 64; ++s) {
        int j = (s << 6) | lane;
        float4 c = crd[j];
#pragma unroll
        for (int r = 0; r < RPW; ++r) {
            // d2 = -2x*cx - 2y*cy - 2z*cz + (|q|^2 + |c|^2), fma chain
            float d2 = fmaf(qx2[r], c.x,
                       fmaf(qy2[r], c.y,
                       fmaf(qz2[r], c.z, qn[r] + c.w)));
            d2 = fmaxf(d2, 0.0f);   // self-pair: tiny +/- rounding -> clamp to +0
            unsigned cur = (__float_as_uint(d2) & 0xFFFFF800u) | (unsigned)j;
#pragma unroll
            for (int k = 0; k < PLM; ++k) {
                unsigned lo = min(lst[r][k], cur);
                cur = max(lst[r][k], cur);
                lst[r][k] = lo;
            }
        }
    }

    // --- C: extraction (4 row-chains interleaved per round) ---
    unsigned mine[RPW];
#pragma unroll
    for (int r = 0; r < RPW; ++r) mine[r] = 0xFFFFFFFFu;

#pragma unroll
    for (int t = 0; t < MTOP; ++t) {
        unsigned a[RPW], m[RPW];
#pragma unroll
        for (int r = 0; r < RPW; ++r) a[r] = dpp_min16_4(lst[r][0]);
#pragma unroll
        for (int r = 0; r < RPW; ++r) m[r] = gather_min(a[r]);
#pragma unroll
        for (int r = 0; r < RPW; ++r) {
            bool rem = (lst[r][0] == m[r]);   // keys unique -> at most one lane
#pragma unroll
            for (int k = 0; k < PLM - 1; ++k) lst[r][k] = rem ? lst[r][k + 1] : lst[r][k];
            lst[r][PLM - 1] = rem ? 0xFFFFFFFFu : lst[r][PLM - 1];
            mine[r] = (lane == t) ? m[r] : mine[r];
        }
    }

    // --- D: exact resort + graph outputs, per row ---
#pragma unroll
    for (int r = 0; r < RPW; ++r) {
        int gi = gi0 + r;
        float4 ci = crd[i0 + r];          // exact query coords (re-read)
        int jf = (int)(mine[r] & (LL - 1));
        float4 cj = crd[jf];
        float D = sqrtf(__fadd_rn(ref_d2(ci.x, ci.y, ci.z, cj.x, cj.y, cj.z), 1e-6f));
        int rank = 0;
#pragma unroll
        for (int t = 0; t < MTOP; ++t) {
            float Dt = __int_as_float(__builtin_amdgcn_readlane(__float_as_int(D), t));
            int   jt = __builtin_amdgcn_readlane(jf, t);
            bool lt = (Dt < D) || (Dt == D && jt < jf);
            rank += lt ? 1 : 0;
        }
        if (lane < MTOP && rank < KNN) {
            int cg = base + jf;
            int e  = gi * KNN + rank;
            out_row[e] = (float)gi;
            out_col[e] = (float)cg;
            int cr = code[gi - base], cc = code[jf];
            int ng = ((cr | cc) & 4) ? 0 : 1;
            int sr = cr & 3, sc = cc & 3;
            out_ctx[e]   = (sr == sc && ng) ? 1.0f : 0.0f;
            out_inter[e] = (sr != sc && ng) ? 1.0f : 0.0f;
            colsL[warp][r][rank] = jf;
        }
    }

    // --- E: edge RBF features, float4 stores ---
    // pass p: 3 edges (slot sE = lane>>4 < 3), chunk g = lane&15 covers
    // feats [4g, 4g+3]: atom = g>>2, t = (g&3)*4 + k.
    {
        int g = lane & 15, sE = lane >> 4;
        int atomE = g >> 2;
        float zk[4];
        float tbE = (float)((g & 3) * 4);
#pragma unroll
        for (int k = 0; k < 4; ++k)
            zk[k] = -(tbE + (float)k) * (20.0f / 15.0f) * 0.8f;  // -mu*0.8
        int rA = warp * RPW;
        if (sE < 3) {
#pragma unroll
            for (int p = 0; p < 3 * RPW; ++p) {
                int r = p / 3;                    // static after unroll
                int q = (p % 3) * 3 + sE;         // 0..8
                int jf = colsL[warp][r][q];
                float4 cj = crd[jf];
                const float* ra = &rowatoms[(rA + r) * 12 + atomE * 3];
                float d = ref_dist(ra[0], ra[1], ra[2], cj.x, cj.y, cj.z);
                float4 v;
                float z0 = fmaf(d, 0.8f, zk[0]); v.x = __expf(-z0 * z0);
                float z1 = fmaf(d, 0.8f, zk[1]); v.y = __expf(-z1 * z1);
                float z2 = fmaf(d, 0.8f, zk[2]); v.z = __expf(-z2 * z2);
                float z3 = fmaf(d, 0.8f, zk[3]); v.w = __expf(-z3 * z3);
                *(float4*)(edge_out + ((size_t)(gi0 + r) * KNN + q) * 64 + g * 4) = v;
            }
        }
    }

    // --- F: node RBF features, single float4 pass ---
    // lane < 48: row rn = lane/12, chunk c4 = lane%12 covers feats [4c4, 4c4+3]
    if (lane < 48) {
        int rn = lane / 12;
        int c4 = lane - rn * 12;
        int aN = c4 >> 2;
        int asrc = (aN == 0) ? 0 : aN + 1;        // atoms 0, 2, 3 vs CA
        float tbN = (float)((c4 & 3) * 4);
        float zn[4];
#pragma unroll
        for (int k = 0; k < 4; ++k)
            zn[k] = -(tbN + (float)k) * (20.0f / 15.0f) * 0.8f;
        const float* ra = &rowatoms[(warp * RPW + rn) * 12 + asrc * 3];
        float4 ca = crd[i0 + rn];
        float d = ref_dist(ra[0], ra[1], ra[2], ca.x, ca.y, ca.z);
        float4 v;
        float z0 = fmaf(d, 0.8f, zn[0]); v.x = __expf(-z0 * z0);
        float z1 = fmaf(d, 0.8f, zn[1]); v.y = __expf(-z1 * z1);
        float z2 = fmaf(d, 0.8f, zn[2]); v.z = __expf(-z2 * z2);
        float z3 = fmaf(d, 0.8f, zn[3]); v.w = __expf(-z3 * z3);
        *(float4*)(node_out + (size_t)(gi0 + rn) * 48 + c4 * 4) = v;
    }
}

// ---------------- launcher ----------------
extern "C" void kernel_launch(void* const* d_in, const int* in_sizes, int n_in,
                              void* d_out, int out_size, void* d_ws, size_t ws_size,
                              hipStream_t stream) {
    const float* X       = (const float*)d_in[0];
    const int*   seg     = (const int*)d_in[1];
    const int*   isg_raw = (const int*)d_in[2];

    float* out = (float*)d_out;
    float* node_out  = out;                                   // [NN*48]
    float* edge_out  = out + (size_t)NN * 48;                 // [NE*64]
    float* row_out   = edge_out + (size_t)NE * 64;            // [NE]
    float* col_out   = row_out + NE;                          // [NE]
    float* ctx_out   = col_out + NE;                          // [NE]
    float* inter_out = ctx_out + NE;                          // [NE]

    hipLaunchKernelGGL(fused_kernel, dim3(NN / ROWS_PB), dim3(TPB), 0, stream,
                       X, seg, isg_raw,
                       node_out, edge_out, row_out, col_out, ctx_out, inter_out);
}

// Round 9
// 53.663 us; speedup vs baseline: 5.6231x; 1.0853x over previous
//
#include <hip/hip_runtime.h>
#include <cstdint>
#include <cstddef>

#define NN   32768
#define BATCH 16
#define LL   2048          // NN / BATCH
#define KNN  9
#define NE   (NN * KNN)    // 294912
#define PLM  5             // per-lane list size
#define MTOP 12            // global candidates extracted before exact resort
#define RPW  4             // rows per wave
#define TPB  1024          // threads per block (16 waves)
#define ROWS_PB ((TPB / 64) * RPW)   // 64 rows per block -> grid = 512

// ---------------- helpers ----------------

// Reference-exact squared distance (non-fused, fixed association) — used only
// in the exact resort and feature phases.
__device__ __forceinline__ float ref_d2(float ax, float ay, float az,
                                        float bx, float by, float bz) {
    float dx = __fsub_rn(ax, bx);
    float dy = __fsub_rn(ay, by);
    float dz = __fsub_rn(az, bz);
    return __fadd_rn(__fadd_rn(__fmul_rn(dx, dx), __fmul_rn(dy, dy)),
                     __fmul_rn(dz, dz));
}

__device__ __forceinline__ float ref_dist(float ax, float ay, float az,
                                          float bx, float by, float bz) {
    return sqrtf(__fadd_rn(ref_d2(ax, ay, az, bx, by, bz), 1e-6f));
}

// DPP row_shr min chain (within rows of 16); invalid lanes take identity.
__device__ __forceinline__ unsigned dpp_min16_4(unsigned x) {
    unsigned t;
    t = (unsigned)__builtin_amdgcn_update_dpp((int)0xFFFFFFFF, (int)x, 0x111, 0xf, 0xf, false);
    x = min(x, t);
    t = (unsigned)__builtin_amdgcn_update_dpp((int)0xFFFFFFFF, (int)x, 0x112, 0xf, 0xf, false);
    x = min(x, t);
    t = (unsigned)__builtin_amdgcn_update_dpp((int)0xFFFFFFFF, (int)x, 0x114, 0xf, 0xf, false);
    x = min(x, t);
    t = (unsigned)__builtin_amdgcn_update_dpp((int)0xFFFFFFFF, (int)x, 0x118, 0xf, 0xf, false);
    x = min(x, t);
    return x;   // lane 15 of each 16-group holds that group's min
}

__device__ __forceinline__ unsigned gather_min(unsigned a) {
    unsigned m0 = min((unsigned)__builtin_amdgcn_readlane((int)a, 15),
                      (unsigned)__builtin_amdgcn_readlane((int)a, 31));
    unsigned m1 = min((unsigned)__builtin_amdgcn_readlane((int)a, 47),
                      (unsigned)__builtin_amdgcn_readlane((int)a, 63));
    return min(m0, m1);   // uniform (SALU)
}

// ---------------- single fused kernel ----------------
//  A) stage CA coords (float4 w/ |p|^2), row atoms, packed seg/isg codes
//  B) scan: per-lane top-5 of truncated-d2|idx keys
//  C) extraction: 12 rounds, 4 row-chains interleaved
//  D) rank assignment: tie-free fast path (ranks = extraction order) or
//     exact (sqrt,j) resort when any two finalists share a trunc-d2 bucket
//  E) edge RBF features: float4 stores
//  F) node RBF features: single float4 pass
__global__ __launch_bounds__(TPB, 8) void fused_kernel(
    const float* __restrict__ X, const int* __restrict__ seg,
    const int* __restrict__ isg_raw,
    float* __restrict__ node_out, float* __restrict__ edge_out,
    float* __restrict__ out_row, float* __restrict__ out_col,
    float* __restrict__ out_ctx, float* __restrict__ out_inter)
{
    __shared__ float4 crd[LL];                 // 32 KB: x, y, z, |p|^2
    __shared__ float rowatoms[ROWS_PB * 12];   // 3 KB: this block's 4-atom rows
    __shared__ unsigned char code[LL];         // 2 KB: seg | (isg<<2)
    __shared__ int colsL[TPB / 64][RPW][KNN];  // finalist local idx per rank
    __shared__ int flag;

    int tid  = threadIdx.x;
    int row0 = blockIdx.x * ROWS_PB;
    int base = row0 & ~(LL - 1);

    // --- A: is_global layout detection (bytes vs int32), staging ---
    if (tid == 0) flag = 0;
    __syncthreads();
    if (tid < 512) {
        // 512 ints cover the batch's byte-layout region; packed 0/1 bytes give
        // a word>1 with P = 1-8^-512 (certain); int32 bools never do.
        unsigned v = (unsigned)isg_raw[(base >> 2) + tid];
        if (v > 1u) atomicOr(&flag, 1);
    }
    if (tid < ROWS_PB * 12)
        rowatoms[tid] = X[(size_t)row0 * 12 + tid];
    __syncthreads();
    bool as_bytes = (flag != 0);
    for (int t = tid; t < LL; t += TPB) {
        const float* p = X + (size_t)(base + t) * 12 + 3;   // atom 1 (CA)
        float x = p[0], y = p[1], z = p[2];
        crd[t] = make_float4(x, y, z, fmaf(x, x, fmaf(y, y, z * z)));
        int ig = as_bytes ? (int)((const unsigned char*)isg_raw)[base + t]
                          : isg_raw[base + t];
        code[t] = (unsigned char)((seg[base + t] & 3) | (ig ? 4 : 0));
    }
    __syncthreads();

    int lane = tid & 63;
    int warp = tid >> 6;
    int gi0  = row0 + warp * RPW;
    int i0   = gi0 - base;

    // hoisted per-row scan constants: (-2x, -2y, -2z, |p|^2)
    float qx2[RPW], qy2[RPW], qz2[RPW], qn[RPW];
#pragma unroll
    for (int r = 0; r < RPW; ++r) {
        float4 ci = crd[i0 + r];
        qx2[r] = -2.0f * ci.x; qy2[r] = -2.0f * ci.y; qz2[r] = -2.0f * ci.z;
        qn[r] = ci.w;
    }

    // --- B: scan ---
    unsigned lst[RPW][PLM];
#pragma unroll
    for (int r = 0; r < RPW; ++r)
#pragma unroll
        for (int k = 0; k < PLM; ++k) lst[r][k] = 0xFFFFFFFFu;

#pragma unroll 8
    for (int s = 0; s < LL / 64; ++s) {
        int j = (s << 6) | lane;
        float4 c = crd[j];
#pragma unroll
        for (int r = 0; r < RPW; ++r) {
            float d2 = fmaf(qx2[r], c.x,
                       fmaf(qy2[r], c.y,
                       fmaf(qz2[r], c.z, qn[r] + c.w)));
            d2 = fmaxf(d2, 0.0f);   // self-pair: tiny +/- rounding -> clamp to +0
            unsigned cur = (__float_as_uint(d2) & 0xFFFFF800u) | (unsigned)j;
#pragma unroll
            for (int k = 0; k < PLM - 1; ++k) {
                unsigned lo = min(lst[r][k], cur);
                cur = max(lst[r][k], cur);
                lst[r][k] = lo;
            }
            lst[r][PLM - 1] = min(lst[r][PLM - 1], cur);   // last slot: min only
        }
    }

    // --- C: extraction (4 row-chains interleaved per round) ---
    unsigned mine[RPW];
#pragma unroll
    for (int r = 0; r < RPW; ++r) mine[r] = 0xFFFFFFFFu;

#pragma unroll
    for (int t = 0; t < MTOP; ++t) {
        unsigned a[RPW], m[RPW];
#pragma unroll
        for (int r = 0; r < RPW; ++r) a[r] = dpp_min16_4(lst[r][0]);
#pragma unroll
        for (int r = 0; r < RPW; ++r) m[r] = gather_min(a[r]);
#pragma unroll
        for (int r = 0; r < RPW; ++r) {
            bool rem = (lst[r][0] == m[r]);   // keys unique -> at most one lane
#pragma unroll
            for (int k = 0; k < PLM - 1; ++k) lst[r][k] = rem ? lst[r][k + 1] : lst[r][k];
            lst[r][PLM - 1] = rem ? 0xFFFFFFFFu : lst[r][PLM - 1];
            mine[r] = (lane == t) ? m[r] : mine[r];
        }
    }

    // --- D: rank assignment + graph outputs, per row ---
#pragma unroll
    for (int r = 0; r < RPW; ++r) {
        int gi = gi0 + r;
        int jf = (int)(mine[r] & (LL - 1));

        // tie check: extraction emitted keys in increasing order; exact order
        // can differ from trunc order only if consecutive finalists share the
        // same truncated-d2 bits (XOR below the 11 index bits).
        unsigned nbr = (unsigned)__builtin_amdgcn_update_dpp(
            (int)0xFFFFFFFF, (int)mine[r], 0x101 /*row_shl:1*/, 0xf, 0xf, false);
        bool tie = (lane < 11) && ((mine[r] ^ nbr) < 2048u);

        int rank;
        if (!__any(tie)) {
            rank = lane;                      // trunc order == exact order
        } else {
            float4 ci = crd[i0 + r];
            float4 cj = crd[jf];
            float D = sqrtf(__fadd_rn(ref_d2(ci.x, ci.y, ci.z, cj.x, cj.y, cj.z), 1e-6f));
            rank = 0;
#pragma unroll
            for (int t = 0; t < MTOP; ++t) {
                float Dt = __int_as_float(__builtin_amdgcn_readlane(__float_as_int(D), t));
                int   jt = __builtin_amdgcn_readlane(jf, t);
                bool lt = (Dt < D) || (Dt == D && jt < jf);
                rank += lt ? 1 : 0;
            }
        }

        if (lane < MTOP && rank < KNN) {
            int cg = base + jf;
            int e  = gi * KNN + rank;
            out_row[e] = (float)gi;
            out_col[e] = (float)cg;
            int cr = code[gi - base], cc = code[jf];
            int ng = ((cr | cc) & 4) ? 0 : 1;
            int sr = cr & 3, sc = cc & 3;
            out_ctx[e]   = (sr == sc && ng) ? 1.0f : 0.0f;
            out_inter[e] = (sr != sc && ng) ? 1.0f : 0.0f;
            colsL[warp][r][rank] = jf;
        }
    }

    // --- E: edge RBF features, float4 stores ---
    {
        int g = lane & 15, sE = lane >> 4;
        int atomE = g >> 2;
        float zk[4];
        float tbE = (float)((g & 3) * 4);
#pragma unroll
        for (int k = 0; k < 4; ++k)
            zk[k] = -(tbE + (float)k) * (20.0f / 15.0f) * 0.8f;  // -mu*0.8
        int rA = warp * RPW;
        if (sE < 3) {
#pragma unroll
            for (int p = 0; p < 3 * RPW; ++p) {
                int r = p / 3;                    // static after unroll
                int q = (p % 3) * 3 + sE;         // 0..8
                int jf = colsL[warp][r][q];
                float4 cj = crd[jf];
                const float* ra = &rowatoms[(rA + r) * 12 + atomE * 3];
                float d = ref_dist(ra[0], ra[1], ra[2], cj.x, cj.y, cj.z);
                float4 v;
                float z0 = fmaf(d, 0.8f, zk[0]); v.x = __expf(-z0 * z0);
                float z1 = fmaf(d, 0.8f, zk[1]); v.y = __expf(-z1 * z1);
                float z2 = fmaf(d, 0.8f, zk[2]); v.z = __expf(-z2 * z2);
                float z3 = fmaf(d, 0.8f, zk[3]); v.w = __expf(-z3 * z3);
                *(float4*)(edge_out + ((size_t)(gi0 + r) * KNN + q) * 64 + g * 4) = v;
            }
        }
    }

    // --- F: node RBF features, single float4 pass ---
    if (lane < 48) {
        int rn = lane / 12;
        int c4 = lane - rn * 12;
        int aN = c4 >> 2;
        int asrc = (aN == 0) ? 0 : aN + 1;        // atoms 0, 2, 3 vs CA
        float tbN = (float)((c4 & 3) * 4);
        float zn[4];
#pragma unroll
        for (int k = 0; k < 4; ++k)
            zn[k] = -(tbN + (float)k) * (20.0f / 15.0f) * 0.8f;
        const float* ra = &rowatoms[(warp * RPW + rn) * 12 + asrc * 3];
        float4 ca = crd[i0 + rn];
        float d = ref_dist(ra[0], ra[1], ra[2], ca.x, ca.y, ca.z);
        float4 v;
        float z0 = fmaf(d, 0.8f, zn[0]); v.x = __expf(-z0 * z0);
        float z1 = fmaf(d, 0.8f, zn[1]); v.y = __expf(-z1 * z1);
        float z2 = fmaf(d, 0.8f, zn[2]); v.z = __expf(-z2 * z2);
        float z3 = fmaf(d, 0.8f, zn[3]); v.w = __expf(-z3 * z3);
        *(float4*)(node_out + (size_t)(gi0 + rn) * 48 + c4 * 4) = v;
    }
}

// ---------------- launcher ----------------
extern "C" void kernel_launch(void* const* d_in, const int* in_sizes, int n_in,
                              void* d_out, int out_size, void* d_ws, size_t ws_size,
                              hipStream_t stream) {
    const float* X       = (const float*)d_in[0];
    const int*   seg     = (const int*)d_in[1];
    const int*   isg_raw = (const int*)d_in[2];

    float* out = (float*)d_out;
    float* node_out  = out;                                   // [NN*48]
    float* edge_out  = out + (size_t)NN * 48;                 // [NE*64]
    float* row_out   = edge_out + (size_t)NE * 64;            // [NE]
    float* col_out   = row_out + NE;                          // [NE]
    float* ctx_out   = col_out + NE;                          // [NE]
    float* inter_out = ctx_out + NE;                          // [NE]

    hipLaunchKernelGGL(fused_kernel, dim3(NN / ROWS_PB), dim3(TPB), 0, stream,
                       X, seg, isg_raw,
                       node_out, edge_out, row_out, col_out, ctx_out, inter_out);
}

// Round 10
// 49.053 us; speedup vs baseline: 6.1515x; 1.0940x over previous
//
#include <hip/hip_runtime.h>
#include <cstdint>
#include <cstddef>

#define NN   32768
#define BATCH 16
#define LL   2048          // NN / BATCH
#define KNN  9
#define NE   (NN * KNN)    // 294912
#define PLM  5             // per-lane list size
#define MTOP 12            // global candidates extracted before exact resort
#define RPW  4             // rows per wave
#define TPB  1024          // threads per block (16 waves)
#define ROWS_PB ((TPB / 64) * RPW)   // 64 rows per block -> grid = 512

// ---------------- helpers ----------------

// Reference-exact squared distance (non-fused, fixed association) — used only
// in the exact resort and feature phases.
__device__ __forceinline__ float ref_d2(float ax, float ay, float az,
                                        float bx, float by, float bz) {
    float dx = __fsub_rn(ax, bx);
    float dy = __fsub_rn(ay, by);
    float dz = __fsub_rn(az, bz);
    return __fadd_rn(__fadd_rn(__fmul_rn(dx, dx), __fmul_rn(dy, dy)),
                     __fmul_rn(dz, dz));
}

__device__ __forceinline__ float ref_dist(float ax, float ay, float az,
                                          float bx, float by, float bz) {
    return sqrtf(__fadd_rn(ref_d2(ax, ay, az, bx, by, bz), 1e-6f));
}

// v_med3_u32: median of 3 (gfx9-lineage VOP3, present on CDNA).
__device__ __forceinline__ unsigned umed3(unsigned a, unsigned b, unsigned c) {
    unsigned r;
    asm("v_med3_u32 %0, %1, %2, %3" : "=v"(r) : "v"(a), "v"(b), "v"(c));
    return r;
}

// 16-lane min butterfly via row_ror (all lanes valid -> no identity constant;
// bound_ctrl=true makes each step eligible for v_min_u32_dpp fusion).
__device__ __forceinline__ unsigned dpp_min16_ror(unsigned x) {
    unsigned t;
    t = (unsigned)__builtin_amdgcn_update_dpp(0, (int)x, 0x121, 0xf, 0xf, true); // ror:1
    x = min(x, t);
    t = (unsigned)__builtin_amdgcn_update_dpp(0, (int)x, 0x122, 0xf, 0xf, true); // ror:2
    x = min(x, t);
    t = (unsigned)__builtin_amdgcn_update_dpp(0, (int)x, 0x124, 0xf, 0xf, true); // ror:4
    x = min(x, t);
    t = (unsigned)__builtin_amdgcn_update_dpp(0, (int)x, 0x128, 0xf, 0xf, true); // ror:8
    x = min(x, t);
    return x;   // every lane holds its 16-group min
}

__device__ __forceinline__ unsigned gather_min(unsigned a) {
    unsigned m0 = min((unsigned)__builtin_amdgcn_readlane((int)a, 15),
                      (unsigned)__builtin_amdgcn_readlane((int)a, 31));
    unsigned m1 = min((unsigned)__builtin_amdgcn_readlane((int)a, 47),
                      (unsigned)__builtin_amdgcn_readlane((int)a, 63));
    return min(m0, m1);   // uniform (SALU)
}

// ---------------- single fused kernel ----------------
//  A) stage CA coords (float4 w/ |p|^2), row atoms, packed seg/isg codes
//  B) scan: per-lane top-5 of truncated-(d2+1)|idx keys, med3 insert
//  C) extraction: 12 rounds, 4 row-chains interleaved (ror-DPP + readlane)
//  D) rank assignment: tie-free fast path or exact (sqrt,j) resort
//  E) edge RBF features: float4 stores
//  F) node RBF features: single float4 pass
__global__ __launch_bounds__(TPB, 8) void fused_kernel(
    const float* __restrict__ X, const int* __restrict__ seg,
    const int* __restrict__ isg_raw,
    float* __restrict__ node_out, float* __restrict__ edge_out,
    float* __restrict__ out_row, float* __restrict__ out_col,
    float* __restrict__ out_ctx, float* __restrict__ out_inter)
{
    __shared__ float4 crd[LL];                 // 32 KB: x, y, z, |p|^2
    __shared__ float rowatoms[ROWS_PB * 12];   // 3 KB: this block's 4-atom rows
    __shared__ unsigned char code[LL];         // 2 KB: seg | (isg<<2)
    __shared__ int colsL[TPB / 64][RPW][KNN];  // finalist local idx per rank
    __shared__ int flag;

    int tid  = threadIdx.x;
    int row0 = blockIdx.x * ROWS_PB;
    int base = row0 & ~(LL - 1);

    // --- A: is_global layout detection (bytes vs int32), staging ---
    if (tid == 0) flag = 0;
    __syncthreads();
    if (tid < 512) {
        // 512 ints cover the batch's byte-layout region; packed 0/1 bytes give
        // a word>1 with P = 1-8^-512 (certain); int32 bools never do.
        unsigned v = (unsigned)isg_raw[(base >> 2) + tid];
        if (v > 1u) atomicOr(&flag, 1);
    }
    if (tid < ROWS_PB * 12)
        rowatoms[tid] = X[(size_t)row0 * 12 + tid];
    __syncthreads();
    bool as_bytes = (flag != 0);
    for (int t = tid; t < LL; t += TPB) {
        const float* p = X + (size_t)(base + t) * 12 + 3;   // atom 1 (CA)
        float x = p[0], y = p[1], z = p[2];
        crd[t] = make_float4(x, y, z, fmaf(x, x, fmaf(y, y, z * z)));
        int ig = as_bytes ? (int)((const unsigned char*)isg_raw)[base + t]
                          : isg_raw[base + t];
        code[t] = (unsigned char)((seg[base + t] & 3) | (ig ? 4 : 0));
    }
    __syncthreads();

    int lane = tid & 63;
    int warp = tid >> 6;
    int gi0  = row0 + warp * RPW;
    int i0   = gi0 - base;

    // hoisted per-row scan constants: (-2x, -2y, -2z, |p|^2 + 1)
    // (+1 bias keeps d2' = d2+1 >= ~1 > 0, so no clamp needed; monotone in d2)
    float qx2[RPW], qy2[RPW], qz2[RPW], qn1[RPW];
#pragma unroll
    for (int r = 0; r < RPW; ++r) {
        float4 ci = crd[i0 + r];
        qx2[r] = -2.0f * ci.x; qy2[r] = -2.0f * ci.y; qz2[r] = -2.0f * ci.z;
        qn1[r] = ci.w + 1.0f;
    }

    // --- B: scan ---
    unsigned lst[RPW][PLM];
#pragma unroll
    for (int r = 0; r < RPW; ++r)
#pragma unroll
        for (int k = 0; k < PLM; ++k) lst[r][k] = 0xFFFFFFFFu;

#pragma unroll 8
    for (int s = 0; s < LL / 64; ++s) {
        int j = (s << 6) | lane;
        float4 c = crd[j];
#pragma unroll
        for (int r = 0; r < RPW; ++r) {
            float d2 = fmaf(qx2[r], c.x,
                       fmaf(qy2[r], c.y,
                       fmaf(qz2[r], c.z, qn1[r] + c.w)));
            unsigned cur = (__float_as_uint(d2) & 0xFFFFF800u) | (unsigned)j;
            // sorted-insert via med3: r0 = min, rk = med3(a[k-1], a[k], cur)
            unsigned n0 = min(lst[r][0], cur);
            unsigned n1 = umed3(lst[r][0], lst[r][1], cur);
            unsigned n2 = umed3(lst[r][1], lst[r][2], cur);
            unsigned n3 = umed3(lst[r][2], lst[r][3], cur);
            unsigned n4 = umed3(lst[r][3], lst[r][4], cur);
            lst[r][0] = n0; lst[r][1] = n1; lst[r][2] = n2;
            lst[r][3] = n3; lst[r][4] = n4;
        }
    }

    // --- C: extraction (4 row-chains interleaved per round) ---
    unsigned mine[RPW];
#pragma unroll
    for (int r = 0; r < RPW; ++r) mine[r] = 0xFFFFFFFFu;

#pragma unroll
    for (int t = 0; t < MTOP; ++t) {
        unsigned a[RPW], m[RPW];
#pragma unroll
        for (int r = 0; r < RPW; ++r) a[r] = dpp_min16_ror(lst[r][0]);
#pragma unroll
        for (int r = 0; r < RPW; ++r) m[r] = gather_min(a[r]);
#pragma unroll
        for (int r = 0; r < RPW; ++r) {
            bool rem = (lst[r][0] == m[r]);   // keys unique -> at most one lane
#pragma unroll
            for (int k = 0; k < PLM - 1; ++k) lst[r][k] = rem ? lst[r][k + 1] : lst[r][k];
            lst[r][PLM - 1] = rem ? 0xFFFFFFFFu : lst[r][PLM - 1];
            mine[r] = (lane == t) ? m[r] : mine[r];
        }
    }

    // --- D: rank assignment + graph outputs, per row ---
#pragma unroll
    for (int r = 0; r < RPW; ++r) {
        int gi = gi0 + r;
        int jf = (int)(mine[r] & (LL - 1));

        // tie check: exact order can differ from trunc order only if
        // consecutive finalists share the same truncated-d2' bits.
        unsigned nbr = (unsigned)__builtin_amdgcn_update_dpp(
            (int)0xFFFFFFFF, (int)mine[r], 0x101 /*row_shl:1*/, 0xf, 0xf, false);
        bool tie = (lane < 11) && ((mine[r] ^ nbr) < 2048u);

        int rank;
        if (!__any(tie)) {
            rank = lane;                      // trunc order == exact order
        } else {
            float4 ci = crd[i0 + r];
            float4 cj = crd[jf];
            float D = sqrtf(__fadd_rn(ref_d2(ci.x, ci.y, ci.z, cj.x, cj.y, cj.z), 1e-6f));
            rank = 0;
#pragma unroll
            for (int t = 0; t < MTOP; ++t) {
                float Dt = __int_as_float(__builtin_amdgcn_readlane(__float_as_int(D), t));
                int   jt = __builtin_amdgcn_readlane(jf, t);
                bool lt = (Dt < D) || (Dt == D && jt < jf);
                rank += lt ? 1 : 0;
            }
        }

        if (lane < MTOP && rank < KNN) {
            int cg = base + jf;
            int e  = gi * KNN + rank;
            out_row[e] = (float)gi;
            out_col[e] = (float)cg;
            int cr = code[gi - base], cc = code[jf];
            int ng = ((cr | cc) & 4) ? 0 : 1;
            int sr = cr & 3, sc = cc & 3;
            out_ctx[e]   = (sr == sc && ng) ? 1.0f : 0.0f;
            out_inter[e] = (sr != sc && ng) ? 1.0f : 0.0f;
            colsL[warp][r][rank] = jf;
        }
    }

    // --- E: edge RBF features, float4 stores ---
    {
        int g = lane & 15, sE = lane >> 4;
        int atomE = g >> 2;
        float zk[4];
        float tbE = (float)((g & 3) * 4);
#pragma unroll
        for (int k = 0; k < 4; ++k)
            zk[k] = -(tbE + (float)k) * (20.0f / 15.0f) * 0.8f;  // -mu*0.8
        int rA = warp * RPW;
        if (sE < 3) {
#pragma unroll
            for (int p = 0; p < 3 * RPW; ++p) {
                int r = p / 3;                    // static after unroll
                int q = (p % 3) * 3 + sE;         // 0..8
                int jf = colsL[warp][r][q];
                float4 cj = crd[jf];
                const float* ra = &rowatoms[(rA + r) * 12 + atomE * 3];
                float d = ref_dist(ra[0], ra[1], ra[2], cj.x, cj.y, cj.z);
                float4 v;
                float z0 = fmaf(d, 0.8f, zk[0]); v.x = __expf(-z0 * z0);
                float z1 = fmaf(d, 0.8f, zk[1]); v.y = __expf(-z1 * z1);
                float z2 = fmaf(d, 0.8f, zk[2]); v.z = __expf(-z2 * z2);
                float z3 = fmaf(d, 0.8f, zk[3]); v.w = __expf(-z3 * z3);
                *(float4*)(edge_out + ((size_t)(gi0 + r) * KNN + q) * 64 + g * 4) = v;
            }
        }
    }

    // --- F: node RBF features, single float4 pass ---
    if (lane < 48) {
        int rn = lane / 12;
        int c4 = lane - rn * 12;
        int aN = c4 >> 2;
        int asrc = (aN == 0) ? 0 : aN + 1;        // atoms 0, 2, 3 vs CA
        float tbN = (float)((c4 & 3) * 4);
        float zn[4];
#pragma unroll
        for (int k = 0; k < 4; ++k)
            zn[k] = -(tbN + (float)k) * (20.0f / 15.0f) * 0.8f;
        const float* ra = &rowatoms[(warp * RPW + rn) * 12 + asrc * 3];
        float4 ca = crd[i0 + rn];
        float d = ref_dist(ra[0], ra[1], ra[2], ca.x, ca.y, ca.z);
        float4 v;
        float z0 = fmaf(d, 0.8f, zn[0]); v.x = __expf(-z0 * z0);
        float z1 = fmaf(d, 0.8f, zn[1]); v.y = __expf(-z1 * z1);
        float z2 = fmaf(d, 0.8f, zn[2]); v.z = __expf(-z2 * z2);
        float z3 = fmaf(d, 0.8f, zn[3]); v.w = __expf(-z3 * z3);
        *(float4*)(node_out + (size_t)(gi0 + rn) * 48 + c4 * 4) = v;
    }
}

// ---------------- launcher ----------------
extern "C" void kernel_launch(void* const* d_in, const int* in_sizes, int n_in,
                              void* d_out, int out_size, void* d_ws, size_t ws_size,
                              hipStream_t stream) {
    const float* X       = (const float*)d_in[0];
    const int*   seg     = (const int*)d_in[1];
    const int*   isg_raw = (const int*)d_in[2];

    float* out = (float*)d_out;
    float* node_out  = out;                                   // [NN*48]
    float* edge_out  = out + (size_t)NN * 48;                 // [NE*64]
    float* row_out   = edge_out + (size_t)NE * 64;            // [NE]
    float* col_out   = row_out + NE;                          // [NE]
    float* ctx_out   = col_out + NE;                          // [NE]
    float* inter_out = ctx_out + NE;                          // [NE]

    hipLaunchKernelGGL(fused_kernel, dim3(NN / ROWS_PB), dim3(TPB), 0, stream,
                       X, seg, isg_raw,
                       node_out, edge_out, row_out, col_out, ctx_out, inter_out);
}